// Round 10
// baseline (5688.061 us; speedup 1.0000x reference)
//
#include <hip/hip_runtime.h>
#include <hip/hip_bf16.h>

// ---------------- types ----------------
typedef __attribute__((ext_vector_type(8))) short bf16x8;   // 8 x bf16 (4 VGPRs)
typedef __attribute__((ext_vector_type(4))) float f32x4;
typedef __attribute__((ext_vector_type(4))) unsigned u32x4;

#define MFMA16(a,b,c) __builtin_amdgcn_mfma_f32_16x16x32_bf16((a),(b),(c),0,0,0)

__device__ __forceinline__ float sigmf(float x){ return 1.f/(1.f + __expf(-x)); }
__device__ __forceinline__ float tanh_fast(float x){
    float e = __expf(-2.f*fabsf(x));
    float t = (1.f-e)/(1.f+e);
    return x < 0.f ? -t : t;
}

#define AS1 __attribute__((address_space(1)))
#define AS3 __attribute__((address_space(3)))
__device__ __forceinline__ void gll16(const void* g, void* l) {
    __builtin_amdgcn_global_load_lds((const AS1 unsigned int*)g, (AS3 unsigned int*)l, 16, 0, 0);
}

// plain cached 16B load via asm (result can't be rematerialized -> stays on-chip)
__device__ __forceinline__ bf16x8 load16_asm(const __hip_bfloat16* p) {
    bf16x8 v;
    asm volatile("global_load_dwordx4 %0, %1, off" : "=v"(v) : "v"(p));
    return v;
}
// L3-coherent 16B load of tagged words (bypass L1+L2)
__device__ __forceinline__ u32x4 load16u_sc(const unsigned* p) {
    u32x4 v;
    asm volatile("global_load_dwordx4 %0, %1, off sc0 sc1" : "=v"(v) : "v"(p) : "memory");
    return v;
}
// L3-coherent 4B store (tagged h word)
__device__ __forceinline__ void store4_sc(unsigned* p, unsigned v) {
    asm volatile("global_store_dword %0, %1, off sc0 sc1" :: "v"(p), "v"(v) : "memory");
}
// cached 2B load (xp stream), asm so issue point is pinned
__device__ __forceinline__ unsigned ld2_g(const __hip_bfloat16* p) {
    unsigned v;
    asm volatile("global_load_ushort %0, %1, off" : "=v"(v) : "v"(p));
    return v;
}

// ---------------- problem constants ----------------
#define B_   64
#define T_   512
#define H_   1000
#define HP   1024        // padded H
#define G3   3072        // 3*HP
#define NC_  2000
#define FEAT_C 500
#define FEAT_P 512
#define NROWS 32768      // B_*T_

// ---------------- ws layout (bytes) ----------------
// hx (tagged h exchange, 1 MB) REUSES the FEAT region: FEAT is fully consumed by
// gemm_xp before init_h/gru_persist run; embed_k rewrites FEAT every launch.
#define OFF_FEAT  ((size_t)0)                       // 32768*512*2      = 33,554,432
#define OFF_HX    OFF_FEAT                          // [2 parity][2*64][1024] u32 = 1 MB
#define OFF_WIHF  (OFF_FEAT + 33554432ull)          // 3072*512*2
#define OFF_WIHB  (OFF_WIHF + 3145728ull)
#define OFF_WHH   (OFF_WIHB + 3145728ull)           // [2][3072][1024] bf16 = 12,582,912
#define OFF_LINW  (OFF_WHH + 12582912ull)           // 2000*2048*2 = 8,192,000
#define OFF_BIHF  (OFF_LINW + 8192000ull)           // 3072*4
#define OFF_BIHB  (OFF_BIHF + 12288ull)
#define OFF_BHH   (OFF_BIHB + 12288ull)             // [2][3072] f32 = 24,576
#define OFF_XP    (OFF_BHH + 24576ull)              // [2][32768][3072] bf16 = 402,653,184
#define OFF_HCAT  (OFF_XP + 402653184ull)           // [64][2048] bf16 = 262,144
#define WS_NEED   (OFF_HCAT + 262144ull)

// ---------------- weight prep ----------------
__global__ void cvt_pad_3h(const float* __restrict__ src, __hip_bfloat16* __restrict__ dst,
                           int C, int Cp) {
    size_t i = (size_t)blockIdx.x*blockDim.x + threadIdx.x;
    size_t total = (size_t)G3 * Cp;
    if (i >= total) return;
    int r = (int)(i / Cp), c = (int)(i % Cp);
    int chunk = r >> 10, j = r & 1023;
    float v = (j < H_ && c < C) ? src[((size_t)chunk*H_ + j)*C + c] : 0.f;
    dst[i] = __float2bfloat16(v);
}

__global__ void cvt_pad(const float* __restrict__ src, __hip_bfloat16* __restrict__ dst,
                        int R, int C, int Cp) {
    size_t i = (size_t)blockIdx.x*blockDim.x + threadIdx.x;
    size_t total = (size_t)R * Cp;
    if (i >= total) return;
    int r = (int)(i / Cp), c = (int)(i % Cp);
    float v = (c < C) ? src[(size_t)r*C + c] : 0.f;
    dst[i] = __float2bfloat16(v);
}

__global__ void pad_b3h(const float* __restrict__ src, float* __restrict__ dst) {
    int i = blockIdx.x*blockDim.x + threadIdx.x;
    if (i >= G3) return;
    int chunk = i >> 10, j = i & 1023;
    dst[i] = (j < H_) ? src[chunk*H_ + j] : 0.f;
}

// ---------------- embedding gather ----------------
__global__ __launch_bounds__(256)
void embed_k(const int* __restrict__ wi, const int* __restrict__ pi, const int* __restrict__ ii,
             const int* __restrict__ ti, const int* __restrict__ mi,
             const float* __restrict__ we, const float* __restrict__ pe, const float* __restrict__ ie,
             const float* __restrict__ te, const float* __restrict__ me,
             __hip_bfloat16* __restrict__ feat) {
    int r = blockIdx.x;          // b*512 + t
    int iw = wi[r], ip = pi[r], ib = ii[r], it = ti[r], im = mi[r];
    #pragma unroll
    for (int q = 0; q < 2; ++q) {
        int c = threadIdx.x + q*256;
        float v;
        if      (c < 300) v = we[(size_t)iw*300 + c];
        else if (c < 350) v = pe[ip*50 + (c-300)];
        else if (c < 400) v = ie[ib*50 + (c-350)];
        else if (c < 450) v = te[it*50 + (c-400)];
        else if (c < 500) v = me[im*50 + (c-450)];
        else              v = 0.f;
        feat[(size_t)r*FEAT_P + c] = __float2bfloat16(v);
    }
}

// ---------------- input projection GEMM (bf16 MFMA, 128x128x64 tiles, global_load_lds) ----------------
__global__ __launch_bounds__(256)
void gemm_xp(const __hip_bfloat16* __restrict__ feat,  // [32768][512]
             const __hip_bfloat16* __restrict__ W,     // [3072][512]
             const float* __restrict__ bias,           // [3072]
             const int* __restrict__ lengths,
             __hip_bfloat16* __restrict__ xp,          // [32768][3072]
             int dir) {
    __shared__ char smem_raw[32768];
    __hip_bfloat16* As = (__hip_bfloat16*)smem_raw;            // [128][64]
    __hip_bfloat16* Bs = (__hip_bfloat16*)(smem_raw + 16384);  // [128][64]
    const int tid = threadIdx.x;
    const int wave = tid >> 6, lane = tid & 63;
    const int bm = blockIdx.x, bn = blockIdx.y;
    const int wm = wave >> 1, wn = wave & 1;

    int arow_src[4];
    #pragma unroll
    for (int q = 0; q < 4; ++q) {
        int flat = q*256 + tid;
        int row = flat >> 3;
        int r_g = bm*128 + row;
        int t = r_g >> 6, b = r_g & 63;
        int src_t;
        if (dir == 0) src_t = t;
        else { int L = lengths[b]; src_t = L - 1 - t; src_t = src_t < 0 ? 0 : src_t; }
        arow_src[q] = b*T_ + src_t;
    }

    f32x4 acc[4][4];
    #pragma unroll
    for (int i = 0; i < 4; ++i)
        #pragma unroll
        for (int j = 0; j < 4; ++j) acc[i][j] = (f32x4){0.f,0.f,0.f,0.f};

    for (int kt = 0; kt < 8; ++kt) {
        int k0 = kt*64;
        #pragma unroll
        for (int q = 0; q < 4; ++q) {
            int flat = q*256 + tid;
            int row = flat >> 3, c8 = flat & 7;
            gll16(feat + (size_t)arow_src[q]*FEAT_P + k0 + c8*8,
                  As + (q*256 + wave*64)*8);
            gll16(W + (size_t)(bn*128 + row)*FEAT_P + k0 + c8*8,
                  Bs + (q*256 + wave*64)*8);
        }
        __syncthreads();
        #pragma unroll
        for (int ks = 0; ks < 2; ++ks) {
            bf16x8 af[4], bfr[4];
            #pragma unroll
            for (int i = 0; i < 4; ++i)
                af[i] = *(const bf16x8*)(As + (wm*64 + i*16 + (lane&15))*64 + ks*32 + (lane>>4)*8);
            #pragma unroll
            for (int j = 0; j < 4; ++j)
                bfr[j] = *(const bf16x8*)(Bs + (wn*64 + j*16 + (lane&15))*64 + ks*32 + (lane>>4)*8);
            #pragma unroll
            for (int i = 0; i < 4; ++i)
                #pragma unroll
                for (int j = 0; j < 4; ++j)
                    acc[i][j] = MFMA16(af[i], bfr[j], acc[i][j]);
        }
        __syncthreads();
    }

    __hip_bfloat16* Cs = (__hip_bfloat16*)smem_raw;  // [128][128]
    #pragma unroll
    for (int j = 0; j < 4; ++j) {
        int col_l = wn*64 + j*16 + (lane & 15);
        float bs = bias[bn*128 + col_l];
        #pragma unroll
        for (int i = 0; i < 4; ++i) {
            #pragma unroll
            for (int r = 0; r < 4; ++r) {
                int row_l = wm*64 + i*16 + (lane>>4)*4 + r;
                Cs[row_l*128 + col_l] = __float2bfloat16(acc[i][j][r] + bs);
            }
        }
    }
    __syncthreads();
    #pragma unroll
    for (int q = 0; q < 8; ++q) {
        int flat = q*256 + tid;       // 16B units, 2048 total
        int row = flat >> 4, c8 = flat & 15;
        bf16x8 v = *(const bf16x8*)(Cs + row*128 + c8*8);
        *(bf16x8*)(xp + (size_t)(bm*128 + row)*G3 + bn*128 + c8*8) = v;
    }
}

// ---------------- tagged-h init: word = (bf16 << 16) | tag0, both parities ----------------
__global__ void init_h(const float* __restrict__ hidden, unsigned* __restrict__ hx) {
    int i = blockIdx.x*blockDim.x + threadIdx.x;   // over 2*64*1024
    if (i >= 2*B_*HP) return;
    int row = i >> 10, j = i & 1023;               // row = dir*64+b
    int dir = row >> 6, b = row & 63;
    float v = (j < H_) ? hidden[((size_t)dir*B_ + b)*H_ + j] : 0.f;
    __hip_bfloat16 bv = __float2bfloat16(v);
    unsigned word = ((unsigned)*reinterpret_cast<unsigned short*>(&bv)) << 16;  // tag 0
    hx[i] = word;                 // parity 0
    hx[2*B_*HP + i] = word;       // parity 1
}

// ---------------- persistent bidirectional GRU recurrence (cooperative) ----------------
// 256 blocks x 512 thr (8 waves). Groups of 64 blocks: g=(dir,bh), 32 batch rows.
// Weights pinned in regs/AGPRs. h exchange = TAGGED DATAFLOW, no barrier:
// word u32 = (h_bf16 << 16) | epoch. Step t: poll parity (t+1)&1 words until all
// tags == t (detection IS the data load), compute, fire-and-forget store of parity
// t&1 words tagged t+1 (no drain -- tag travels with value; monotone tags, no ABA).
// Ping-pong overwrite safety: a block writes tag t+2 only after its block-wide
// sync on tag-t+1 polls, which transitively requires every reader wave of the
// overwritten word to have consumed tag t (all-to-all within the group).
__global__ __launch_bounds__(512, 2)
void gru_persist(const __hip_bfloat16* __restrict__ whh,   // [2][3072][1024]
                 const float* __restrict__ bhh,            // [2][3072]
                 const __hip_bfloat16* __restrict__ xp,    // [2][32768][3072]
                 const int* __restrict__ lengths,
                 const float* __restrict__ hidden,         // [2][64][1000]
                 unsigned* __restrict__ hx,                // [2 parity][2*64][1024] tagged
                 __hip_bfloat16* __restrict__ hcat,        // [64][2048]
                 float* __restrict__ hid_o) {              // d_out + 64*2000
    __shared__ float part[2][4][3][256];   // [bg][kh][gate][lane*4 + r]
    const int blk = blockIdx.x;
    const int r8  = blk & 7, q8 = blk >> 3;
    const int g   = r8 >> 1;                 // group 0..3
    const int dir = g >> 1, bh = g & 1;
    const int ug  = q8*2 + (r8 & 1);         // unit group 0..63
    const int w    = threadIdx.x >> 6;
    const int lane = threadIdx.x & 63;
    const int bg  = w >> 2;     // 0..1
    const int kh  = w & 3;      // 0..3 (K-quarter)
    const int u   = lane & 15;
    const int rg  = lane >> 4;  // 0..3

    const int j   = ug*16 + u;                      // hidden unit (0..1023)
    const int bA  = bh*32 + bg*16 + u;              // A-fragment batch row
    const int bF  = bh*32 + bg*16 + rg*4 + kh;      // finalize batch row
    const int myLen  = lengths[bF];
    const int lenBlk = lengths[bh*32];              // group-uniform (sorted desc)

    const float bhr = bhh[dir*G3 + j];
    const float bhz = bhh[dir*G3 + HP + j];
    const float bhn = bhh[dir*G3 + 2*HP + j];
    float hreg = (j < H_) ? hidden[((size_t)dir*B_ + bF)*H_ + j] : 0.f;

    // weights -> registers (3 gates x 8 K-slices of this wave's K-quarter), pinned via asm
    bf16x8 wf0[8], wf1[8], wf2[8];
    {
        const __hip_bfloat16* wb = whh + (size_t)dir*G3*HP + (size_t)j*HP + kh*256 + rg*8;
        #pragma unroll
        for (int ks = 0; ks < 8; ++ks) {
            wf0[ks] = load16_asm(wb + ks*32);
            wf1[ks] = load16_asm(wb + (size_t)HP*HP + ks*32);
            wf2[ks] = load16_asm(wb + (size_t)2*HP*HP + ks*32);
        }
        asm volatile("s_waitcnt vmcnt(0)" ::: "memory");
        __builtin_amdgcn_sched_barrier(0);
    }

    const size_t hrowA = (size_t)(dir*B_ + bA)*HP + kh*256 + rg*8;   // u32 index
    const size_t hidxF = (size_t)(dir*B_ + bF)*HP + j;               // u32 index
    const size_t xbase = (size_t)dir*NROWS*G3 + (size_t)bF*G3 + j;

    // prefetch xp(t=0) scalars (drained by the first poll's vmcnt(0))
    unsigned pxr, pxz, pxn;
    {
        const __hip_bfloat16* x0 = xp + xbase;
        pxr = ld2_g(x0); pxz = ld2_g(x0 + HP); pxn = ld2_g(x0 + 2*HP);
    }

    for (int t = 0; t < lenBlk; ++t) {
        // ---- S1: poll-fused h load: parity (t+1)&1, expect tag t ----
        const unsigned* hrd = hx + (size_t)((t+1)&1)*2*B_*HP + hrowA;
        const unsigned tgt = (unsigned)t;
        u32x4 wv[16];
        for (;;) {
            #pragma unroll
            for (int ks = 0; ks < 8; ++ks) {
                wv[2*ks]   = load16u_sc(hrd + ks*32);
                wv[2*ks+1] = load16u_sc(hrd + ks*32 + 4);
            }
            asm volatile("s_waitcnt vmcnt(0)" ::: "memory");
            unsigned acc = 0;
            #pragma unroll
            for (int q = 0; q < 16; ++q)
                #pragma unroll
                for (int e = 0; e < 4; ++e) acc |= (wv[q][e] ^ tgt) & 0xFFFFu;
            if (__all((int)(acc == 0))) break;
        }
        __builtin_amdgcn_sched_barrier(0);

        // ---- extract bf16 fragments (h in high 16 of each word) ----
        bf16x8 af[8];
        #pragma unroll
        for (int ks = 0; ks < 8; ++ks) {
            union { unsigned u4[4]; bf16x8 v; } cv;
            cv.u4[0] = (wv[2*ks][0]   >> 16) | (wv[2*ks][1]   & 0xFFFF0000u);
            cv.u4[1] = (wv[2*ks][2]   >> 16) | (wv[2*ks][3]   & 0xFFFF0000u);
            cv.u4[2] = (wv[2*ks+1][0] >> 16) | (wv[2*ks+1][1] & 0xFFFF0000u);
            cv.u4[3] = (wv[2*ks+1][2] >> 16) | (wv[2*ks+1][3] & 0xFFFF0000u);
            af[ks] = cv.v;
        }

        // ---- S2: MFMA over this wave's K-quarter ----
        f32x4 a0 = {0.f,0.f,0.f,0.f}, a1 = {0.f,0.f,0.f,0.f}, a2 = {0.f,0.f,0.f,0.f};
        #pragma unroll
        for (int ks = 0; ks < 8; ++ks) {
            a0 = MFMA16(af[ks], wf0[ks], a0);
            a1 = MFMA16(af[ks], wf1[ks], a1);
            a2 = MFMA16(af[ks], wf2[ks], a2);
        }

        // consume prefetched xp(t)
        float xr = __uint_as_float(pxr << 16);
        float xz = __uint_as_float(pxz << 16);
        float xn = __uint_as_float(pxn << 16);

        // ---- S3: K-partial reduce via LDS ----
        *(f32x4*)&part[bg][kh][0][lane*4] = a0;
        *(f32x4*)&part[bg][kh][1][lane*4] = a1;
        *(f32x4*)&part[bg][kh][2][lane*4] = a2;
        __syncthreads();
        float sr = 0.f, sz = 0.f, sn = 0.f;
        #pragma unroll
        for (int q = 0; q < 4; ++q) {
            sr += part[bg][q][0][lane*4 + kh];
            sz += part[bg][q][1][lane*4 + kh];
            sn += part[bg][q][2][lane*4 + kh];
        }

        // ---- S4: gates + fire-and-forget tagged store (parity t&1, tag t+1) ----
        float rr = sigmf(xr + sr + bhr);
        float zz = sigmf(xz + sz + bhz);
        float nn = tanh_fast(xn + rr*(sn + bhn));
        float hnew = (t < myLen) ? ((1.f - zz)*nn + zz*hreg) : hreg;
        hreg = hnew;
        {
            __hip_bfloat16 hb = __float2bfloat16(hnew);
            unsigned word = (((unsigned)*reinterpret_cast<unsigned short*>(&hb)) << 16)
                            | (unsigned)(t + 1);
            store4_sc(hx + (size_t)(t & 1)*2*B_*HP + hidxF, word);
        }

        // prefetch xp(t+1) (in flight; drained by next poll's vmcnt(0))
        if (t + 1 < lenBlk) {
            const __hip_bfloat16* xnp = xp + xbase + (size_t)(t+1)*B_*G3;
            pxr = ld2_g(xnp); pxz = ld2_g(xnp + HP); pxn = ld2_g(xnp + 2*HP);
        }
        __syncthreads();   // protect `part` reuse across steps
    }

    // outputs straight from registers (+ zero hcat tail cols 2000..2047)
    if (j < H_) {
        hid_o[((size_t)dir*B_ + bF)*H_ + j] = hreg;
        hcat[(size_t)bF*2048 + dir*H_ + j] = __float2bfloat16(hreg);
    } else {
        hcat[(size_t)bF*2048 + 2000 + dir*24 + (j - H_)] = __float2bfloat16(0.f);
    }
}

// ---------------- final linear + BN ----------------
__global__ __launch_bounds__(256)
void lin_bn_k(const __hip_bfloat16* __restrict__ hcat,  // [64][2048]
              const __hip_bfloat16* __restrict__ linw,  // [2000][2048]
              const float* __restrict__ lin_b, const float* __restrict__ gamma,
              const float* __restrict__ beta, const float* __restrict__ mean,
              const float* __restrict__ var,
              float* __restrict__ out) {                // [64][2000]
    __shared__ __hip_bfloat16 wlds[16*2056];
    const int n0 = blockIdx.x*16;
    const int tid = threadIdx.x;
    #pragma unroll
    for (int q = 0; q < 16; ++q) {
        int flat8 = q*256 + tid;
        int row = flat8 >> 8, c8 = flat8 & 255;
        bf16x8 v = *(const bf16x8*)(linw + (size_t)(n0+row)*2048 + c8*8);
        *(bf16x8*)(wlds + row*2056 + c8*8) = v;
    }
    __syncthreads();
    const int wave = tid >> 6, lane = tid & 63;
    const int mrow = wave*16 + (lane & 15);
    f32x4 acc = {0.f,0.f,0.f,0.f};
    for (int ks = 0; ks < 64; ++ks) {
        bf16x8 a = *(const bf16x8*)(hcat + (size_t)mrow*2048 + ks*32 + (lane>>4)*8);
        bf16x8 b = *(const bf16x8*)(wlds + (lane&15)*2056 + ks*32 + (lane>>4)*8);
        acc = MFMA16(a, b, acc);
    }
    const int c = n0 + (lane & 15);
    const float g = gamma[c], bt = beta[c], mn = mean[c], lb = lin_b[c];
    const float iv = rsqrtf(var[c] + 1e-5f);
    #pragma unroll
    for (int r = 0; r < 4; ++r) {
        int b_ = wave*16 + (lane>>4)*4 + r;
        float logit = acc[r] + lb;
        out[(size_t)b_*NC_ + c] = g*(logit - mn)*iv + bt;
    }
}

// ---------------- host ----------------
extern "C" void kernel_launch(void* const* d_in, const int* in_sizes, int n_in,
                              void* d_out, int out_size, void* d_ws, size_t ws_size,
                              hipStream_t stream) {
    const int*   wi      = (const int*)d_in[0];
    const int*   pi      = (const int*)d_in[1];
    const int*   ii      = (const int*)d_in[2];
    const int*   ti      = (const int*)d_in[3];
    const int*   mi      = (const int*)d_in[4];
    const int*   lengths = (const int*)d_in[5];
    const float* hidden  = (const float*)d_in[6];
    const float* we      = (const float*)d_in[7];
    const float* pe      = (const float*)d_in[8];
    const float* ie      = (const float*)d_in[9];
    const float* te      = (const float*)d_in[10];
    const float* me      = (const float*)d_in[11];
    const float* w_ih_f  = (const float*)d_in[12];
    const float* w_hh_f  = (const float*)d_in[13];
    const float* b_ih_f  = (const float*)d_in[14];
    const float* b_hh_f  = (const float*)d_in[15];
    const float* w_ih_b  = (const float*)d_in[16];
    const float* w_hh_b  = (const float*)d_in[17];
    const float* b_ih_b  = (const float*)d_in[18];
    const float* b_hh_b  = (const float*)d_in[19];
    const float* lin_w   = (const float*)d_in[20];
    const float* lin_b   = (const float*)d_in[21];
    const float* gamma   = (const float*)d_in[22];
    const float* beta    = (const float*)d_in[23];
    const float* mean    = (const float*)d_in[24];
    const float* var     = (const float*)d_in[25];
    float* out = (float*)d_out;

    if (ws_size < WS_NEED) return;

    char* ws = (char*)d_ws;
    __hip_bfloat16* FEAT = (__hip_bfloat16*)(ws + OFF_FEAT);
    unsigned*       HX   = (unsigned*)(ws + OFF_HX);          // aliases FEAT (safe: FEAT consumed first)
    __hip_bfloat16* WIHF = (__hip_bfloat16*)(ws + OFF_WIHF);
    __hip_bfloat16* WIHB = (__hip_bfloat16*)(ws + OFF_WIHB);
    __hip_bfloat16* WHH  = (__hip_bfloat16*)(ws + OFF_WHH);   // [2][3072][1024]
    __hip_bfloat16* LINW = (__hip_bfloat16*)(ws + OFF_LINW);
    float* BIHF = (float*)(ws + OFF_BIHF);
    float* BIHB = (float*)(ws + OFF_BIHB);
    float* BHH  = (float*)(ws + OFF_BHH);                      // [2][3072]
    __hip_bfloat16* XP   = (__hip_bfloat16*)(ws + OFF_XP);     // [2][32768][3072]
    __hip_bfloat16* HCAT = (__hip_bfloat16*)(ws + OFF_HCAT);
    float* HIDO = out + (size_t)B_*NC_;

    // weight prep
    cvt_pad_3h<<<(G3*512 + 255)/256, 256, 0, stream>>>(w_ih_f, WIHF, FEAT_C, FEAT_P);
    cvt_pad_3h<<<(G3*512 + 255)/256, 256, 0, stream>>>(w_ih_b, WIHB, FEAT_C, FEAT_P);
    cvt_pad_3h<<<(G3*1024 + 255)/256, 256, 0, stream>>>(w_hh_f, WHH, H_, HP);
    cvt_pad_3h<<<(G3*1024 + 255)/256, 256, 0, stream>>>(w_hh_b, WHH + (size_t)G3*HP, H_, HP);
    cvt_pad<<<(NC_*2048 + 255)/256, 256, 0, stream>>>(lin_w, LINW, NC_, NC_, 2048);
    pad_b3h<<<(G3 + 255)/256, 256, 0, stream>>>(b_ih_f, BIHF);
    pad_b3h<<<(G3 + 255)/256, 256, 0, stream>>>(b_ih_b, BIHB);
    pad_b3h<<<(G3 + 255)/256, 256, 0, stream>>>(b_hh_f, BHH);
    pad_b3h<<<(G3 + 255)/256, 256, 0, stream>>>(b_hh_b, BHH + G3);

    // embeddings
    embed_k<<<NROWS, 256, 0, stream>>>(wi, pi, ii, ti, mi, we, pe, ie, te, me, FEAT);

    // input projections (both directions) -- consume FEAT
    dim3 gg(NROWS/128, G3/128);
    gemm_xp<<<gg, 256, 0, stream>>>(FEAT, WIHF, BIHF, lengths, XP, 0);
    gemm_xp<<<gg, 256, 0, stream>>>(FEAT, WIHB, BIHB, lengths, XP + (size_t)NROWS*G3, 1);

    // recurrence (single persistent cooperative kernel, tagged dataflow)
    init_h<<<(2*B_*HP + 255)/256, 256, 0, stream>>>(hidden, HX);
    {
        void* args[] = { (void*)&WHH, (void*)&BHH, (void*)&XP, (void*)&lengths,
                         (void*)&hidden, (void*)&HX, (void*)&HCAT, (void*)&HIDO };
        hipLaunchCooperativeKernel((const void*)gru_persist, dim3(256), dim3(512),
                                   args, 0, stream);
    }

    // head
    lin_bn_k<<<NC_/16, 256, 0, stream>>>(HCAT, LINW, lin_b, gamma, beta, mean, var, out);
}

// Round 11
// 3623.683 us; speedup vs baseline: 1.5697x; 1.5697x over previous
//
#include <hip/hip_runtime.h>
#include <hip/hip_bf16.h>

// ---------------- types ----------------
typedef __attribute__((ext_vector_type(8))) short bf16x8;   // 8 x bf16 (4 VGPRs)
typedef __attribute__((ext_vector_type(4))) float f32x4;

#define MFMA16(a,b,c) __builtin_amdgcn_mfma_f32_16x16x32_bf16((a),(b),(c),0,0,0)

__device__ __forceinline__ float sigmf(float x){ return 1.f/(1.f + __expf(-x)); }
__device__ __forceinline__ float tanh_fast(float x){
    float e = __expf(-2.f*fabsf(x));
    float t = (1.f-e)/(1.f+e);
    return x < 0.f ? -t : t;
}

#define AS1 __attribute__((address_space(1)))
#define AS3 __attribute__((address_space(3)))
__device__ __forceinline__ void gll16(const void* g, void* l) {
    __builtin_amdgcn_global_load_lds((const AS1 unsigned int*)g, (AS3 unsigned int*)l, 16, 0, 0);
}

// plain cached 16B load via asm (result can't be rematerialized -> stays on-chip)
__device__ __forceinline__ bf16x8 load16_asm(const __hip_bfloat16* p) {
    bf16x8 v;
    asm volatile("global_load_dwordx4 %0, %1, off" : "=v"(v) : "v"(p));
    return v;
}
// L3-coherent 16B load: bypass L1+L2 (sc0 sc1)
__device__ __forceinline__ bf16x8 load16_sc(const __hip_bfloat16* p) {
    bf16x8 v;
    asm volatile("global_load_dwordx4 %0, %1, off sc0 sc1" : "=v"(v) : "v"(p) : "memory");
    return v;
}
// L3-coherent 2B store (write-through past L1/L2)
__device__ __forceinline__ void store2_sc(__hip_bfloat16* p, float v) {
    __hip_bfloat16 b = __float2bfloat16(v);
    unsigned int u = *reinterpret_cast<unsigned short*>(&b);
    asm volatile("global_store_short %0, %1, off sc0 sc1" :: "v"(p), "v"(u) : "memory");
}
// L3-coherent 4B poll load
__device__ __forceinline__ unsigned poll_sc(const unsigned* p) {
    unsigned v;
    asm volatile("global_load_dword %0, %1, off sc0 sc1\n\ts_waitcnt vmcnt(0)"
                 : "=v"(v) : "v"(p) : "memory");
    return v;
}
// cached 2B load (xp stream), asm so issue point is pinned
__device__ __forceinline__ unsigned ld2_g(const __hip_bfloat16* p) {
    unsigned v;
    asm volatile("global_load_ushort %0, %1, off" : "=v"(v) : "v"(p));
    return v;
}

// ---------------- problem constants ----------------
#define B_   64
#define T_   512
#define H_   1000
#define HP   1024        // padded H
#define G3   3072        // 3*HP
#define NC_  2000
#define FEAT_C 500
#define FEAT_P 512
#define NROWS 32768      // B_*T_

// ---------------- ws layout (bytes) ----------------
#define OFF_FEAT  ((size_t)0)                       // 32768*512*2      = 33,554,432
#define OFF_WIHF  (OFF_FEAT + 33554432ull)          // 3072*512*2
#define OFF_WIHB  (OFF_WIHF + 3145728ull)
#define OFF_WHH   (OFF_WIHB + 3145728ull)           // [2][3072][1024] bf16 = 12,582,912
#define OFF_LINW  (OFF_WHH + 12582912ull)           // 2000*2048*2 = 8,192,000
#define OFF_BIHF  (OFF_LINW + 8192000ull)           // 3072*4
#define OFF_BIHB  (OFF_BIHF + 12288ull)
#define OFF_BHH   (OFF_BIHB + 12288ull)             // [2][3072] f32 = 24,576
#define OFF_XP    (OFF_BHH + 24576ull)              // [2][32768][3072] bf16 = 402,653,184
#define OFF_HBF   (OFF_XP + 402653184ull)           // [2 parity][2*64][1024] bf16 = 524,288
#define OFF_HCAT  (OFF_HBF + 524288ull)             // [64][2048] bf16 = 262,144
#define OFF_BAR   (OFF_HCAT + 262144ull)            // 4 groups x 2048 B = 8192
#define WS_NEED   (OFF_BAR + 8192ull)

// ---------------- weight prep ----------------
__global__ void cvt_pad_3h(const float* __restrict__ src, __hip_bfloat16* __restrict__ dst,
                           int C, int Cp) {
    size_t i = (size_t)blockIdx.x*blockDim.x + threadIdx.x;
    size_t total = (size_t)G3 * Cp;
    if (i >= total) return;
    int r = (int)(i / Cp), c = (int)(i % Cp);
    int chunk = r >> 10, j = r & 1023;
    float v = (j < H_ && c < C) ? src[((size_t)chunk*H_ + j)*C + c] : 0.f;
    dst[i] = __float2bfloat16(v);
}

__global__ void cvt_pad(const float* __restrict__ src, __hip_bfloat16* __restrict__ dst,
                        int R, int C, int Cp) {
    size_t i = (size_t)blockIdx.x*blockDim.x + threadIdx.x;
    size_t total = (size_t)R * Cp;
    if (i >= total) return;
    int r = (int)(i / Cp), c = (int)(i % Cp);
    float v = (c < C) ? src[(size_t)r*C + c] : 0.f;
    dst[i] = __float2bfloat16(v);
}

__global__ void pad_b3h(const float* __restrict__ src, float* __restrict__ dst) {
    int i = blockIdx.x*blockDim.x + threadIdx.x;
    if (i >= G3) return;
    int chunk = i >> 10, j = i & 1023;
    dst[i] = (j < H_) ? src[chunk*H_ + j] : 0.f;
}

// ---------------- embedding gather ----------------
__global__ __launch_bounds__(256)
void embed_k(const int* __restrict__ wi, const int* __restrict__ pi, const int* __restrict__ ii,
             const int* __restrict__ ti, const int* __restrict__ mi,
             const float* __restrict__ we, const float* __restrict__ pe, const float* __restrict__ ie,
             const float* __restrict__ te, const float* __restrict__ me,
             __hip_bfloat16* __restrict__ feat) {
    int r = blockIdx.x;          // b*512 + t
    int iw = wi[r], ip = pi[r], ib = ii[r], it = ti[r], im = mi[r];
    #pragma unroll
    for (int q = 0; q < 2; ++q) {
        int c = threadIdx.x + q*256;
        float v;
        if      (c < 300) v = we[(size_t)iw*300 + c];
        else if (c < 350) v = pe[ip*50 + (c-300)];
        else if (c < 400) v = ie[ib*50 + (c-350)];
        else if (c < 450) v = te[it*50 + (c-400)];
        else if (c < 500) v = me[im*50 + (c-450)];
        else              v = 0.f;
        feat[(size_t)r*FEAT_P + c] = __float2bfloat16(v);
    }
}

// ---------------- input projection GEMM (bf16 MFMA, 128x128x64 tiles, global_load_lds) ----------------
__global__ __launch_bounds__(256)
void gemm_xp(const __hip_bfloat16* __restrict__ feat,  // [32768][512]
             const __hip_bfloat16* __restrict__ W,     // [3072][512]
             const float* __restrict__ bias,           // [3072]
             const int* __restrict__ lengths,
             __hip_bfloat16* __restrict__ xp,          // [32768][3072]
             int dir) {
    __shared__ char smem_raw[32768];
    __hip_bfloat16* As = (__hip_bfloat16*)smem_raw;            // [128][64]
    __hip_bfloat16* Bs = (__hip_bfloat16*)(smem_raw + 16384);  // [128][64]
    const int tid = threadIdx.x;
    const int wave = tid >> 6, lane = tid & 63;
    const int bm = blockIdx.x, bn = blockIdx.y;
    const int wm = wave >> 1, wn = wave & 1;

    int arow_src[4];
    #pragma unroll
    for (int q = 0; q < 4; ++q) {
        int flat = q*256 + tid;
        int row = flat >> 3;
        int r_g = bm*128 + row;
        int t = r_g >> 6, b = r_g & 63;
        int src_t;
        if (dir == 0) src_t = t;
        else { int L = lengths[b]; src_t = L - 1 - t; src_t = src_t < 0 ? 0 : src_t; }
        arow_src[q] = b*T_ + src_t;
    }

    f32x4 acc[4][4];
    #pragma unroll
    for (int i = 0; i < 4; ++i)
        #pragma unroll
        for (int j = 0; j < 4; ++j) acc[i][j] = (f32x4){0.f,0.f,0.f,0.f};

    for (int kt = 0; kt < 8; ++kt) {
        int k0 = kt*64;
        #pragma unroll
        for (int q = 0; q < 4; ++q) {
            int flat = q*256 + tid;
            int row = flat >> 3, c8 = flat & 7;
            gll16(feat + (size_t)arow_src[q]*FEAT_P + k0 + c8*8,
                  As + (q*256 + wave*64)*8);
            gll16(W + (size_t)(bn*128 + row)*FEAT_P + k0 + c8*8,
                  Bs + (q*256 + wave*64)*8);
        }
        __syncthreads();
        #pragma unroll
        for (int ks = 0; ks < 2; ++ks) {
            bf16x8 af[4], bfr[4];
            #pragma unroll
            for (int i = 0; i < 4; ++i)
                af[i] = *(const bf16x8*)(As + (wm*64 + i*16 + (lane&15))*64 + ks*32 + (lane>>4)*8);
            #pragma unroll
            for (int j = 0; j < 4; ++j)
                bfr[j] = *(const bf16x8*)(Bs + (wn*64 + j*16 + (lane&15))*64 + ks*32 + (lane>>4)*8);
            #pragma unroll
            for (int i = 0; i < 4; ++i)
                #pragma unroll
                for (int j = 0; j < 4; ++j)
                    acc[i][j] = MFMA16(af[i], bfr[j], acc[i][j]);
        }
        __syncthreads();
    }

    __hip_bfloat16* Cs = (__hip_bfloat16*)smem_raw;  // [128][128]
    #pragma unroll
    for (int j = 0; j < 4; ++j) {
        int col_l = wn*64 + j*16 + (lane & 15);
        float bs = bias[bn*128 + col_l];
        #pragma unroll
        for (int i = 0; i < 4; ++i) {
            #pragma unroll
            for (int r = 0; r < 4; ++r) {
                int row_l = wm*64 + i*16 + (lane>>4)*4 + r;
                Cs[row_l*128 + col_l] = __float2bfloat16(acc[i][j][r] + bs);
            }
        }
    }
    __syncthreads();
    #pragma unroll
    for (int q = 0; q < 8; ++q) {
        int flat = q*256 + tid;       // 16B units, 2048 total
        int row = flat >> 4, c8 = flat & 15;
        bf16x8 v = *(const bf16x8*)(Cs + row*128 + c8*8);
        *(bf16x8*)(xp + (size_t)(bm*128 + row)*G3 + bn*128 + c8*8) = v;
    }
}

// ---------------- h bf16 ping-pong init ----------------
__global__ void init_h(const float* __restrict__ hidden, __hip_bfloat16* __restrict__ hbf) {
    int i = blockIdx.x*blockDim.x + threadIdx.x;   // over 2*64*1024
    if (i >= 2*B_*HP) return;
    int row = i >> 10, j = i & 1023;               // row = dir*64+b
    int dir = row >> 6, b = row & 63;
    float v = (j < H_) ? hidden[((size_t)dir*B_ + b)*H_ + j] : 0.f;
    __hip_bfloat16 bv = __float2bfloat16(v);
    hbf[i] = bv;                 // parity 0
    hbf[2*B_*HP + i] = bv;       // parity 1
}

__global__ void bar_init(unsigned* bar) {
    int i = blockIdx.x*blockDim.x + threadIdx.x;   // 8 x 256 = 2048 u32 = 8 KB
    if (i < 2048) bar[i] = 0u;
}

// ---------------- persistent bidirectional GRU recurrence (cooperative) ----------------
// 256 blocks x 512 thr (8 waves). Barrier groups of 64 blocks: g=(dir,bh).
// Weights pinned in regs/AGPRs via asm loads. h exchange via L3 (sc0 sc1).
// Barrier (FLAT tree): arrive = 64 atomicAdds spread over 8 lines (parallel RMW,
// return unused); release = EVERY block's wave-0 polls the 8 count lines directly
// (lane&7 -> 8 unique dwords after same-address coalescing, __all(v >= 8*(t+1))).
// No aggregator, no flag hop: detection ~0.5 L3 RT after last arrive instead of ~2.
// Monotone counts + >= threshold: racing-ahead-safe, deadlock-free by construction.
// xp(t+1) scalars prefetched into regs across the barrier.
__global__ __launch_bounds__(512, 2)
void gru_persist(const __hip_bfloat16* __restrict__ whh,   // [2][3072][1024]
                 const float* __restrict__ bhh,            // [2][3072]
                 const __hip_bfloat16* __restrict__ xp,    // [2][32768][3072]
                 const int* __restrict__ lengths,
                 const float* __restrict__ hidden,         // [2][64][1000]
                 __hip_bfloat16* __restrict__ hbf,         // [2][128][1024]
                 __hip_bfloat16* __restrict__ hcat,        // [64][2048]
                 float* __restrict__ hid_o,                // d_out + 64*2000
                 unsigned* __restrict__ bar) {
    __shared__ float part[2][4][3][256];   // [bg][kh][gate][lane*4 + r]
    const int blk = blockIdx.x;
    const int r8  = blk & 7, q8 = blk >> 3;
    const int g   = r8 >> 1;                 // barrier group 0..3
    const int dir = g >> 1, bh = g & 1;
    const int ug  = q8*2 + (r8 & 1);         // unit group 0..63
    const int w    = threadIdx.x >> 6;
    const int lane = threadIdx.x & 63;
    const int bg  = w >> 2;     // 0..1
    const int kh  = w & 3;      // 0..3 (K-quarter)
    const int u   = lane & 15;
    const int rg  = lane >> 4;  // 0..3

    const int j   = ug*16 + u;                      // hidden unit (0..1023)
    const int bA  = bh*32 + bg*16 + u;              // A-fragment batch row
    const int bF  = bh*32 + bg*16 + rg*4 + kh;      // finalize batch row
    const int myLen  = lengths[bF];
    const int lenBlk = lengths[bh*32];              // group-uniform (sorted desc)

    unsigned* cntg = bar + g*512;                   // 8 arrive lines, 128B stride

    const float bhr = bhh[dir*G3 + j];
    const float bhz = bhh[dir*G3 + HP + j];
    const float bhn = bhh[dir*G3 + 2*HP + j];
    float hreg = (j < H_) ? hidden[((size_t)dir*B_ + bF)*H_ + j] : 0.f;

    // weights -> registers (3 gates x 8 K-slices of this wave's K-quarter), pinned via asm
    bf16x8 wf0[8], wf1[8], wf2[8];
    {
        const __hip_bfloat16* wb = whh + (size_t)dir*G3*HP + (size_t)j*HP + kh*256 + rg*8;
        #pragma unroll
        for (int ks = 0; ks < 8; ++ks) {
            wf0[ks] = load16_asm(wb + ks*32);
            wf1[ks] = load16_asm(wb + (size_t)HP*HP + ks*32);
            wf2[ks] = load16_asm(wb + (size_t)2*HP*HP + ks*32);
        }
        asm volatile("s_waitcnt vmcnt(0)" ::: "memory");
        __builtin_amdgcn_sched_barrier(0);
    }

    const size_t hrowA = (size_t)(dir*B_ + bA)*HP + kh*256 + rg*8;
    const size_t hidxF = (size_t)(dir*B_ + bF)*HP + j;
    const size_t xbase = (size_t)dir*NROWS*G3 + (size_t)bF*G3 + j;

    // prefetch xp(t=0) scalars (drained by the first S1 vmcnt(0))
    unsigned pxr, pxz, pxn;
    {
        const __hip_bfloat16* x0 = xp + xbase;
        pxr = ld2_g(x0); pxz = ld2_g(x0 + HP); pxn = ld2_g(x0 + 2*HP);
    }

    for (int t = 0; t < lenBlk; ++t) {
        const int cur = t & 1, prev = cur ^ 1;
        // h A-fragments from L3 (written cross-XCD last step)
        const __hip_bfloat16* ha = hbf + (size_t)prev*2*B_*HP + hrowA;
        bf16x8 af[8];
        #pragma unroll
        for (int ks = 0; ks < 8; ++ks) af[ks] = load16_sc(ha + ks*32);
        asm volatile("s_waitcnt vmcnt(0)" ::: "memory");
        __builtin_amdgcn_sched_barrier(0);

        f32x4 a0 = {0.f,0.f,0.f,0.f}, a1 = {0.f,0.f,0.f,0.f}, a2 = {0.f,0.f,0.f,0.f};
        #pragma unroll
        for (int ks = 0; ks < 8; ++ks) {
            a0 = MFMA16(af[ks], wf0[ks], a0);
            a1 = MFMA16(af[ks], wf1[ks], a1);
            a2 = MFMA16(af[ks], wf2[ks], a2);
        }

        // consume prefetched xp(t)
        float xr = __uint_as_float(pxr << 16);
        float xz = __uint_as_float(pxz << 16);
        float xn = __uint_as_float(pxn << 16);

        *(f32x4*)&part[bg][kh][0][lane*4] = a0;
        *(f32x4*)&part[bg][kh][1][lane*4] = a1;
        *(f32x4*)&part[bg][kh][2][lane*4] = a2;
        __syncthreads();
        float sr = 0.f, sz = 0.f, sn = 0.f;
        #pragma unroll
        for (int q = 0; q < 4; ++q) {
            sr += part[bg][q][0][lane*4 + kh];
            sz += part[bg][q][1][lane*4 + kh];
            sn += part[bg][q][2][lane*4 + kh];
        }
        float rr = sigmf(xr + sr + bhr);
        float zz = sigmf(xz + sz + bhz);
        float nn = tanh_fast(xn + rr*(sn + bhn));
        float hnew = (t < myLen) ? ((1.f - zz)*nn + zz*hreg) : hreg;
        hreg = hnew;
        store2_sc(hbf + (size_t)cur*2*B_*HP + hidxF, hnew);   // through to L3
        asm volatile("s_waitcnt vmcnt(0)" ::: "memory");      // per-wave drain
        __syncthreads();                                      // all waves drained

        if (t + 1 < lenBlk) {                                 // group-uniform predicate
            // prefetch xp(t+1); stays in flight across the barrier
            {
                const __hip_bfloat16* xnp = xp + xbase + (size_t)(t+1)*B_*G3;
                pxr = ld2_g(xnp); pxz = ld2_g(xnp + HP); pxn = ld2_g(xnp + 2*HP);
            }
            if (w == 0) {
                const unsigned tgt = (unsigned)(t + 1);
                if (lane == 0) atomicAdd(cntg + (ug >> 3)*32, 1u);   // parallel arrive
                const unsigned thr = 8u*tgt;
                for (;;) {
                    unsigned v = poll_sc(cntg + (lane & 7)*32);      // direct count poll
                    if (__all((int)(v >= thr))) break;
                }
            }
            __syncthreads();
        }
    }

    // outputs straight from registers (+ zero hcat tail cols 2000..2047)
    if (j < H_) {
        hid_o[((size_t)dir*B_ + bF)*H_ + j] = hreg;
        hcat[(size_t)bF*2048 + dir*H_ + j] = __float2bfloat16(hreg);
    } else {
        hcat[(size_t)bF*2048 + 2000 + dir*24 + (j - H_)] = __float2bfloat16(0.f);
    }
}

// ---------------- final linear + BN ----------------
__global__ __launch_bounds__(256)
void lin_bn_k(const __hip_bfloat16* __restrict__ hcat,  // [64][2048]
              const __hip_bfloat16* __restrict__ linw,  // [2000][2048]
              const float* __restrict__ lin_b, const float* __restrict__ gamma,
              const float* __restrict__ beta, const float* __restrict__ mean,
              const float* __restrict__ var,
              float* __restrict__ out) {                // [64][2000]
    __shared__ __hip_bfloat16 wlds[16*2056];
    const int n0 = blockIdx.x*16;
    const int tid = threadIdx.x;
    #pragma unroll
    for (int q = 0; q < 16; ++q) {
        int flat8 = q*256 + tid;
        int row = flat8 >> 8, c8 = flat8 & 255;
        bf16x8 v = *(const bf16x8*)(linw + (size_t)(n0+row)*2048 + c8*8);
        *(bf16x8*)(wlds + row*2056 + c8*8) = v;
    }
    __syncthreads();
    const int wave = tid >> 6, lane = tid & 63;
    const int mrow = wave*16 + (lane & 15);
    f32x4 acc = {0.f,0.f,0.f,0.f};
    for (int ks = 0; ks < 64; ++ks) {
        bf16x8 a = *(const bf16x8*)(hcat + (size_t)mrow*2048 + ks*32 + (lane>>4)*8);
        bf16x8 b = *(const bf16x8*)(wlds + (lane&15)*2056 + ks*32 + (lane>>4)*8);
        acc = MFMA16(a, b, acc);
    }
    const int c = n0 + (lane & 15);
    const float g = gamma[c], bt = beta[c], mn = mean[c], lb = lin_b[c];
    const float iv = rsqrtf(var[c] + 1e-5f);
    #pragma unroll
    for (int r = 0; r < 4; ++r) {
        int b_ = wave*16 + (lane>>4)*4 + r;
        float logit = acc[r] + lb;
        out[(size_t)b_*NC_ + c] = g*(logit - mn)*iv + bt;
    }
}

// ---------------- host ----------------
extern "C" void kernel_launch(void* const* d_in, const int* in_sizes, int n_in,
                              void* d_out, int out_size, void* d_ws, size_t ws_size,
                              hipStream_t stream) {
    const int*   wi      = (const int*)d_in[0];
    const int*   pi      = (const int*)d_in[1];
    const int*   ii      = (const int*)d_in[2];
    const int*   ti      = (const int*)d_in[3];
    const int*   mi      = (const int*)d_in[4];
    const int*   lengths = (const int*)d_in[5];
    const float* hidden  = (const float*)d_in[6];
    const float* we      = (const float*)d_in[7];
    const float* pe      = (const float*)d_in[8];
    const float* ie      = (const float*)d_in[9];
    const float* te      = (const float*)d_in[10];
    const float* me      = (const float*)d_in[11];
    const float* w_ih_f  = (const float*)d_in[12];
    const float* w_hh_f  = (const float*)d_in[13];
    const float* b_ih_f  = (const float*)d_in[14];
    const float* b_hh_f  = (const float*)d_in[15];
    const float* w_ih_b  = (const float*)d_in[16];
    const float* w_hh_b  = (const float*)d_in[17];
    const float* b_ih_b  = (const float*)d_in[18];
    const float* b_hh_b  = (const float*)d_in[19];
    const float* lin_w   = (const float*)d_in[20];
    const float* lin_b   = (const float*)d_in[21];
    const float* gamma   = (const float*)d_in[22];
    const float* beta    = (const float*)d_in[23];
    const float* mean    = (const float*)d_in[24];
    const float* var     = (const float*)d_in[25];
    float* out = (float*)d_out;

    if (ws_size < WS_NEED) return;

    char* ws = (char*)d_ws;
    __hip_bfloat16* FEAT = (__hip_bfloat16*)(ws + OFF_FEAT);
    __hip_bfloat16* WIHF = (__hip_bfloat16*)(ws + OFF_WIHF);
    __hip_bfloat16* WIHB = (__hip_bfloat16*)(ws + OFF_WIHB);
    __hip_bfloat16* WHH  = (__hip_bfloat16*)(ws + OFF_WHH);   // [2][3072][1024]
    __hip_bfloat16* LINW = (__hip_bfloat16*)(ws + OFF_LINW);
    float* BIHF = (float*)(ws + OFF_BIHF);
    float* BIHB = (float*)(ws + OFF_BIHB);
    float* BHH  = (float*)(ws + OFF_BHH);                      // [2][3072]
    __hip_bfloat16* XP   = (__hip_bfloat16*)(ws + OFF_XP);     // [2][32768][3072]
    __hip_bfloat16* HBF  = (__hip_bfloat16*)(ws + OFF_HBF);
    __hip_bfloat16* HCAT = (__hip_bfloat16*)(ws + OFF_HCAT);
    unsigned* BAR = (unsigned*)(ws + OFF_BAR);
    float* HIDO = out + (size_t)B_*NC_;

    // weight prep
    cvt_pad_3h<<<(G3*512 + 255)/256, 256, 0, stream>>>(w_ih_f, WIHF, FEAT_C, FEAT_P);
    cvt_pad_3h<<<(G3*512 + 255)/256, 256, 0, stream>>>(w_ih_b, WIHB, FEAT_C, FEAT_P);
    cvt_pad_3h<<<(G3*1024 + 255)/256, 256, 0, stream>>>(w_hh_f, WHH, H_, HP);
    cvt_pad_3h<<<(G3*1024 + 255)/256, 256, 0, stream>>>(w_hh_b, WHH + (size_t)G3*HP, H_, HP);
    cvt_pad<<<(NC_*2048 + 255)/256, 256, 0, stream>>>(lin_w, LINW, NC_, NC_, 2048);
    pad_b3h<<<(G3 + 255)/256, 256, 0, stream>>>(b_ih_f, BIHF);
    pad_b3h<<<(G3 + 255)/256, 256, 0, stream>>>(b_ih_b, BIHB);
    pad_b3h<<<(G3 + 255)/256, 256, 0, stream>>>(b_hh_f, BHH);
    pad_b3h<<<(G3 + 255)/256, 256, 0, stream>>>(b_hh_b, BHH + G3);

    // embeddings
    embed_k<<<NROWS, 256, 0, stream>>>(wi, pi, ii, ti, mi, we, pe, ie, te, me, FEAT);

    // input projections (both directions)
    dim3 gg(NROWS/128, G3/128);
    gemm_xp<<<gg, 256, 0, stream>>>(FEAT, WIHF, BIHF, lengths, XP, 0);
    gemm_xp<<<gg, 256, 0, stream>>>(FEAT, WIHB, BIHB, lengths, XP + (size_t)NROWS*G3, 1);

    // recurrence (single persistent cooperative kernel)
    init_h<<<(2*B_*HP + 255)/256, 256, 0, stream>>>(hidden, HBF);
    bar_init<<<8, 256, 0, stream>>>(BAR);
    {
        void* args[] = { (void*)&WHH, (void*)&BHH, (void*)&XP, (void*)&lengths,
                         (void*)&hidden, (void*)&HBF, (void*)&HCAT, (void*)&HIDO, (void*)&BAR };
        hipLaunchCooperativeKernel((const void*)gru_persist, dim3(256), dim3(512),
                                   args, 0, stream);
    }

    // head
    lin_bn_k<<<NC_/16, 256, 0, stream>>>(HCAT, LINW, lin_b, gamma, beta, mean, var, out);
}

// Round 12
// 2844.453 us; speedup vs baseline: 1.9997x; 1.2739x over previous
//
#include <hip/hip_runtime.h>
#include <hip/hip_bf16.h>

// ---------------- types ----------------
typedef __attribute__((ext_vector_type(8))) short bf16x8;   // 8 x bf16 (4 VGPRs)
typedef __attribute__((ext_vector_type(4))) float f32x4;

#define MFMA16(a,b,c) __builtin_amdgcn_mfma_f32_16x16x32_bf16((a),(b),(c),0,0,0)

__device__ __forceinline__ float sigmf(float x){ return 1.f/(1.f + __expf(-x)); }
__device__ __forceinline__ float tanh_fast(float x){
    float e = __expf(-2.f*fabsf(x));
    float t = (1.f-e)/(1.f+e);
    return x < 0.f ? -t : t;
}

#define AS1 __attribute__((address_space(1)))
#define AS3 __attribute__((address_space(3)))
__device__ __forceinline__ void gll16(const void* g, void* l) {
    __builtin_amdgcn_global_load_lds((const AS1 unsigned int*)g, (AS3 unsigned int*)l, 16, 0, 0);
}

// plain cached 16B load via asm (result can't be rematerialized -> stays on-chip)
__device__ __forceinline__ bf16x8 load16_asm(const __hip_bfloat16* p) {
    bf16x8 v;
    asm volatile("global_load_dwordx4 %0, %1, off" : "=v"(v) : "v"(p));
    return v;
}
// L3-coherent 16B load: bypass L1+L2 (sc0 sc1)
__device__ __forceinline__ bf16x8 load16_sc(const __hip_bfloat16* p) {
    bf16x8 v;
    asm volatile("global_load_dwordx4 %0, %1, off sc0 sc1" : "=v"(v) : "v"(p) : "memory");
    return v;
}
// L3-coherent 2B store (write-through past L1/L2)
__device__ __forceinline__ void store2_sc(__hip_bfloat16* p, float v) {
    __hip_bfloat16 b = __float2bfloat16(v);
    unsigned int u = *reinterpret_cast<unsigned short*>(&b);
    asm volatile("global_store_short %0, %1, off sc0 sc1" :: "v"(p), "v"(u) : "memory");
}
// L3-coherent 4B store
__device__ __forceinline__ void store4_sc(unsigned* p, unsigned v) {
    asm volatile("global_store_dword %0, %1, off sc0 sc1" :: "v"(p), "v"(v) : "memory");
}
// L3-coherent 4B poll load
__device__ __forceinline__ unsigned poll_sc(const unsigned* p) {
    unsigned v;
    asm volatile("global_load_dword %0, %1, off sc0 sc1\n\ts_waitcnt vmcnt(0)"
                 : "=v"(v) : "v"(p) : "memory");
    return v;
}
// cached 2B load (xp stream), asm so issue point is pinned
__device__ __forceinline__ unsigned ld2_g(const __hip_bfloat16* p) {
    unsigned v;
    asm volatile("global_load_ushort %0, %1, off" : "=v"(v) : "v"(p));
    return v;
}

// ---------------- problem constants ----------------
#define B_   64
#define T_   512
#define H_   1000
#define HP   1024        // padded H
#define G3   3072        // 3*HP
#define NC_  2000
#define FEAT_C 500
#define FEAT_P 512
#define NROWS 32768      // B_*T_

// ---------------- ws layout (bytes) ----------------
#define OFF_FEAT  ((size_t)0)                       // 32768*512*2      = 33,554,432
#define OFF_WIHF  (OFF_FEAT + 33554432ull)          // 3072*512*2
#define OFF_WIHB  (OFF_WIHF + 3145728ull)
#define OFF_WHH   (OFF_WIHB + 3145728ull)           // [2][3072][1024] bf16 = 12,582,912
#define OFF_LINW  (OFF_WHH + 12582912ull)           // 2000*2048*2 = 8,192,000
#define OFF_BIHF  (OFF_LINW + 8192000ull)           // 3072*4
#define OFF_BIHB  (OFF_BIHF + 12288ull)
#define OFF_BHH   (OFF_BIHB + 12288ull)             // [2][3072] f32 = 24,576
#define OFF_XP    (OFF_BHH + 24576ull)              // [2][32768][3072] bf16 = 402,653,184
#define OFF_HBF   (OFF_XP + 402653184ull)           // [2 parity][2*64][1024] bf16 = 524,288
#define OFF_HCAT  (OFF_HBF + 524288ull)             // [64][2048] bf16 = 262,144
#define OFF_BAR   (OFF_HCAT + 262144ull)            // 4 groups x 2048 B = 8192
#define WS_NEED   (OFF_BAR + 8192ull)

// ---------------- weight prep ----------------
__global__ void cvt_pad_3h(const float* __restrict__ src, __hip_bfloat16* __restrict__ dst,
                           int C, int Cp) {
    size_t i = (size_t)blockIdx.x*blockDim.x + threadIdx.x;
    size_t total = (size_t)G3 * Cp;
    if (i >= total) return;
    int r = (int)(i / Cp), c = (int)(i % Cp);
    int chunk = r >> 10, j = r & 1023;
    float v = (j < H_ && c < C) ? src[((size_t)chunk*H_ + j)*C + c] : 0.f;
    dst[i] = __float2bfloat16(v);
}

__global__ void cvt_pad(const float* __restrict__ src, __hip_bfloat16* __restrict__ dst,
                        int R, int C, int Cp) {
    size_t i = (size_t)blockIdx.x*blockDim.x + threadIdx.x;
    size_t total = (size_t)R * Cp;
    if (i >= total) return;
    int r = (int)(i / Cp), c = (int)(i % Cp);
    float v = (c < C) ? src[(size_t)r*C + c] : 0.f;
    dst[i] = __float2bfloat16(v);
}

__global__ void pad_b3h(const float* __restrict__ src, float* __restrict__ dst) {
    int i = blockIdx.x*blockDim.x + threadIdx.x;
    if (i >= G3) return;
    int chunk = i >> 10, j = i & 1023;
    dst[i] = (j < H_) ? src[chunk*H_ + j] : 0.f;
}

// ---------------- embedding gather ----------------
__global__ __launch_bounds__(256)
void embed_k(const int* __restrict__ wi, const int* __restrict__ pi, const int* __restrict__ ii,
             const int* __restrict__ ti, const int* __restrict__ mi,
             const float* __restrict__ we, const float* __restrict__ pe, const float* __restrict__ ie,
             const float* __restrict__ te, const float* __restrict__ me,
             __hip_bfloat16* __restrict__ feat) {
    int r = blockIdx.x;          // b*512 + t
    int iw = wi[r], ip = pi[r], ib = ii[r], it = ti[r], im = mi[r];
    #pragma unroll
    for (int q = 0; q < 2; ++q) {
        int c = threadIdx.x + q*256;
        float v;
        if      (c < 300) v = we[(size_t)iw*300 + c];
        else if (c < 350) v = pe[ip*50 + (c-300)];
        else if (c < 400) v = ie[ib*50 + (c-350)];
        else if (c < 450) v = te[it*50 + (c-400)];
        else if (c < 500) v = me[im*50 + (c-450)];
        else              v = 0.f;
        feat[(size_t)r*FEAT_P + c] = __float2bfloat16(v);
    }
}

// ---------------- input projection GEMM (bf16 MFMA, 128x128x64 tiles, global_load_lds) ----------------
__global__ __launch_bounds__(256)
void gemm_xp(const __hip_bfloat16* __restrict__ feat,  // [32768][512]
             const __hip_bfloat16* __restrict__ W,     // [3072][512]
             const float* __restrict__ bias,           // [3072]
             const int* __restrict__ lengths,
             __hip_bfloat16* __restrict__ xp,          // [32768][3072]
             int dir) {
    __shared__ char smem_raw[32768];
    __hip_bfloat16* As = (__hip_bfloat16*)smem_raw;            // [128][64]
    __hip_bfloat16* Bs = (__hip_bfloat16*)(smem_raw + 16384);  // [128][64]
    const int tid = threadIdx.x;
    const int wave = tid >> 6, lane = tid & 63;
    const int bm = blockIdx.x, bn = blockIdx.y;
    const int wm = wave >> 1, wn = wave & 1;

    int arow_src[4];
    #pragma unroll
    for (int q = 0; q < 4; ++q) {
        int flat = q*256 + tid;
        int row = flat >> 3;
        int r_g = bm*128 + row;
        int t = r_g >> 6, b = r_g & 63;
        int src_t;
        if (dir == 0) src_t = t;
        else { int L = lengths[b]; src_t = L - 1 - t; src_t = src_t < 0 ? 0 : src_t; }
        arow_src[q] = b*T_ + src_t;
    }

    f32x4 acc[4][4];
    #pragma unroll
    for (int i = 0; i < 4; ++i)
        #pragma unroll
        for (int j = 0; j < 4; ++j) acc[i][j] = (f32x4){0.f,0.f,0.f,0.f};

    for (int kt = 0; kt < 8; ++kt) {
        int k0 = kt*64;
        #pragma unroll
        for (int q = 0; q < 4; ++q) {
            int flat = q*256 + tid;
            int row = flat >> 3, c8 = flat & 7;
            gll16(feat + (size_t)arow_src[q]*FEAT_P + k0 + c8*8,
                  As + (q*256 + wave*64)*8);
            gll16(W + (size_t)(bn*128 + row)*FEAT_P + k0 + c8*8,
                  Bs + (q*256 + wave*64)*8);
        }
        __syncthreads();
        #pragma unroll
        for (int ks = 0; ks < 2; ++ks) {
            bf16x8 af[4], bfr[4];
            #pragma unroll
            for (int i = 0; i < 4; ++i)
                af[i] = *(const bf16x8*)(As + (wm*64 + i*16 + (lane&15))*64 + ks*32 + (lane>>4)*8);
            #pragma unroll
            for (int j = 0; j < 4; ++j)
                bfr[j] = *(const bf16x8*)(Bs + (wn*64 + j*16 + (lane&15))*64 + ks*32 + (lane>>4)*8);
            #pragma unroll
            for (int i = 0; i < 4; ++i)
                #pragma unroll
                for (int j = 0; j < 4; ++j)
                    acc[i][j] = MFMA16(af[i], bfr[j], acc[i][j]);
        }
        __syncthreads();
    }

    __hip_bfloat16* Cs = (__hip_bfloat16*)smem_raw;  // [128][128]
    #pragma unroll
    for (int j = 0; j < 4; ++j) {
        int col_l = wn*64 + j*16 + (lane & 15);
        float bs = bias[bn*128 + col_l];
        #pragma unroll
        for (int i = 0; i < 4; ++i) {
            #pragma unroll
            for (int r = 0; r < 4; ++r) {
                int row_l = wm*64 + i*16 + (lane>>4)*4 + r;
                Cs[row_l*128 + col_l] = __float2bfloat16(acc[i][j][r] + bs);
            }
        }
    }
    __syncthreads();
    #pragma unroll
    for (int q = 0; q < 8; ++q) {
        int flat = q*256 + tid;       // 16B units, 2048 total
        int row = flat >> 4, c8 = flat & 15;
        bf16x8 v = *(const bf16x8*)(Cs + row*128 + c8*8);
        *(bf16x8*)(xp + (size_t)(bm*128 + row)*G3 + bn*128 + c8*8) = v;
    }
}

// ---------------- h bf16 ping-pong init ----------------
__global__ void init_h(const float* __restrict__ hidden, __hip_bfloat16* __restrict__ hbf) {
    int i = blockIdx.x*blockDim.x + threadIdx.x;   // over 2*64*1024
    if (i >= 2*B_*HP) return;
    int row = i >> 10, j = i & 1023;               // row = dir*64+b
    int dir = row >> 6, b = row & 63;
    float v = (j < H_) ? hidden[((size_t)dir*B_ + b)*H_ + j] : 0.f;
    __hip_bfloat16 bv = __float2bfloat16(v);
    hbf[i] = bv;                 // parity 0
    hbf[2*B_*HP + i] = bv;       // parity 1
}

__global__ void bar_init(unsigned* bar) {
    int i = blockIdx.x*blockDim.x + threadIdx.x;   // 8 x 256 = 2048 u32 = 8 KB
    if (i < 2048) bar[i] = 0u;
}

// ---------------- persistent bidirectional GRU recurrence (cooperative) ----------------
// 256 blocks x 512 thr (8 waves). Barrier groups of 64 blocks: g=(dir,bh).
// Weights pinned in regs/AGPRs via asm loads. h exchange via L3 (sc0 sc1).
// Barrier (two-level tree, BEST MEASURED 4.72us/step): arrive = 64 atomicAdds
// spread over 8 lines; aggregator block (ug==0) polls the 8 lines with one
// 64-lane load + __all, then single-writer-stores the release flag; remaining
// blocks tight-poll the read-only flag line. Monotone counters, no resets.
// xp(t+1) scalars prefetched into regs across the barrier.
__global__ __launch_bounds__(512, 2)
void gru_persist(const __hip_bfloat16* __restrict__ whh,   // [2][3072][1024]
                 const float* __restrict__ bhh,            // [2][3072]
                 const __hip_bfloat16* __restrict__ xp,    // [2][32768][3072]
                 const int* __restrict__ lengths,
                 const float* __restrict__ hidden,         // [2][64][1000]
                 __hip_bfloat16* __restrict__ hbf,         // [2][128][1024]
                 __hip_bfloat16* __restrict__ hcat,        // [64][2048]
                 float* __restrict__ hid_o,                // d_out + 64*2000
                 unsigned* __restrict__ bar) {
    __shared__ float part[2][4][3][256];   // [bg][kh][gate][lane*4 + r]
    const int blk = blockIdx.x;
    const int r8  = blk & 7, q8 = blk >> 3;
    const int g   = r8 >> 1;                 // barrier group 0..3
    const int dir = g >> 1, bh = g & 1;
    const int ug  = q8*2 + (r8 & 1);         // unit group 0..63
    const int w    = threadIdx.x >> 6;
    const int lane = threadIdx.x & 63;
    const int bg  = w >> 2;     // 0..1
    const int kh  = w & 3;      // 0..3 (K-quarter)
    const int u   = lane & 15;
    const int rg  = lane >> 4;  // 0..3

    const int j   = ug*16 + u;                      // hidden unit (0..1023)
    const int bA  = bh*32 + bg*16 + u;              // A-fragment batch row
    const int bF  = bh*32 + bg*16 + rg*4 + kh;      // finalize batch row
    const int myLen  = lengths[bF];
    const int lenBlk = lengths[bh*32];              // group-uniform (sorted desc)

    unsigned* cntg  = bar + g*512;                  // 8 arrive lines, 128B stride
    unsigned* flagp = bar + g*512 + 256;            // release flag line

    const float bhr = bhh[dir*G3 + j];
    const float bhz = bhh[dir*G3 + HP + j];
    const float bhn = bhh[dir*G3 + 2*HP + j];
    float hreg = (j < H_) ? hidden[((size_t)dir*B_ + bF)*H_ + j] : 0.f;

    // weights -> registers (3 gates x 8 K-slices of this wave's K-quarter), pinned via asm
    bf16x8 wf0[8], wf1[8], wf2[8];
    {
        const __hip_bfloat16* wb = whh + (size_t)dir*G3*HP + (size_t)j*HP + kh*256 + rg*8;
        #pragma unroll
        for (int ks = 0; ks < 8; ++ks) {
            wf0[ks] = load16_asm(wb + ks*32);
            wf1[ks] = load16_asm(wb + (size_t)HP*HP + ks*32);
            wf2[ks] = load16_asm(wb + (size_t)2*HP*HP + ks*32);
        }
        asm volatile("s_waitcnt vmcnt(0)" ::: "memory");
        __builtin_amdgcn_sched_barrier(0);
    }

    const size_t hrowA = (size_t)(dir*B_ + bA)*HP + kh*256 + rg*8;
    const size_t hidxF = (size_t)(dir*B_ + bF)*HP + j;
    const size_t xbase = (size_t)dir*NROWS*G3 + (size_t)bF*G3 + j;

    // prefetch xp(t=0) scalars (drained by the first S1 vmcnt(0))
    unsigned pxr, pxz, pxn;
    {
        const __hip_bfloat16* x0 = xp + xbase;
        pxr = ld2_g(x0); pxz = ld2_g(x0 + HP); pxn = ld2_g(x0 + 2*HP);
    }

    for (int t = 0; t < lenBlk; ++t) {
        const int cur = t & 1, prev = cur ^ 1;
        // h A-fragments from L3 (written cross-XCD last step)
        const __hip_bfloat16* ha = hbf + (size_t)prev*2*B_*HP + hrowA;
        bf16x8 af[8];
        #pragma unroll
        for (int ks = 0; ks < 8; ++ks) af[ks] = load16_sc(ha + ks*32);
        asm volatile("s_waitcnt vmcnt(0)" ::: "memory");
        __builtin_amdgcn_sched_barrier(0);

        f32x4 a0 = {0.f,0.f,0.f,0.f}, a1 = {0.f,0.f,0.f,0.f}, a2 = {0.f,0.f,0.f,0.f};
        #pragma unroll
        for (int ks = 0; ks < 8; ++ks) {
            a0 = MFMA16(af[ks], wf0[ks], a0);
            a1 = MFMA16(af[ks], wf1[ks], a1);
            a2 = MFMA16(af[ks], wf2[ks], a2);
        }

        // consume prefetched xp(t)
        float xr = __uint_as_float(pxr << 16);
        float xz = __uint_as_float(pxz << 16);
        float xn = __uint_as_float(pxn << 16);

        *(f32x4*)&part[bg][kh][0][lane*4] = a0;
        *(f32x4*)&part[bg][kh][1][lane*4] = a1;
        *(f32x4*)&part[bg][kh][2][lane*4] = a2;
        __syncthreads();
        float sr = 0.f, sz = 0.f, sn = 0.f;
        #pragma unroll
        for (int q = 0; q < 4; ++q) {
            sr += part[bg][q][0][lane*4 + kh];
            sz += part[bg][q][1][lane*4 + kh];
            sn += part[bg][q][2][lane*4 + kh];
        }
        float rr = sigmf(xr + sr + bhr);
        float zz = sigmf(xz + sz + bhz);
        float nn = tanh_fast(xn + rr*(sn + bhn));
        float hnew = (t < myLen) ? ((1.f - zz)*nn + zz*hreg) : hreg;
        hreg = hnew;
        store2_sc(hbf + (size_t)cur*2*B_*HP + hidxF, hnew);   // through to L3
        asm volatile("s_waitcnt vmcnt(0)" ::: "memory");      // per-wave drain
        __syncthreads();                                      // all waves drained

        if (t + 1 < lenBlk) {                                 // group-uniform predicate
            // prefetch xp(t+1); stays in flight across the barrier
            {
                const __hip_bfloat16* xnp = xp + xbase + (size_t)(t+1)*B_*G3;
                pxr = ld2_g(xnp); pxz = ld2_g(xnp + HP); pxn = ld2_g(xnp + 2*HP);
            }
            if (w == 0) {
                const unsigned tgt = (unsigned)(t + 1);
                if (lane == 0) atomicAdd(cntg + (ug >> 3)*32, 1u);   // parallel arrive
                if (ug == 0) {
                    // aggregator: one 64-lane load covers the 8 arrive lines
                    for (;;) {
                        unsigned v = poll_sc(cntg + (lane & 7)*32);
                        if (__all((int)(v >= 8u*tgt))) break;
                    }
                    if (lane == 0) store4_sc(flagp, tgt);            // single-writer release
                } else {
                    if (lane == 0) { while (poll_sc(flagp) < tgt) { } }
                }
            }
            __syncthreads();
        }
    }

    // outputs straight from registers (+ zero hcat tail cols 2000..2047)
    if (j < H_) {
        hid_o[((size_t)dir*B_ + bF)*H_ + j] = hreg;
        hcat[(size_t)bF*2048 + dir*H_ + j] = __float2bfloat16(hreg);
    } else {
        hcat[(size_t)bF*2048 + 2000 + dir*24 + (j - H_)] = __float2bfloat16(0.f);
    }
}

// ---------------- final linear + BN ----------------
__global__ __launch_bounds__(256)
void lin_bn_k(const __hip_bfloat16* __restrict__ hcat,  // [64][2048]
              const __hip_bfloat16* __restrict__ linw,  // [2000][2048]
              const float* __restrict__ lin_b, const float* __restrict__ gamma,
              const float* __restrict__ beta, const float* __restrict__ mean,
              const float* __restrict__ var,
              float* __restrict__ out) {                // [64][2000]
    __shared__ __hip_bfloat16 wlds[16*2056];
    const int n0 = blockIdx.x*16;
    const int tid = threadIdx.x;
    #pragma unroll
    for (int q = 0; q < 16; ++q) {
        int flat8 = q*256 + tid;
        int row = flat8 >> 8, c8 = flat8 & 255;
        bf16x8 v = *(const bf16x8*)(linw + (size_t)(n0+row)*2048 + c8*8);
        *(bf16x8*)(wlds + row*2056 + c8*8) = v;
    }
    __syncthreads();
    const int wave = tid >> 6, lane = tid & 63;
    const int mrow = wave*16 + (lane & 15);
    f32x4 acc = {0.f,0.f,0.f,0.f};
    for (int ks = 0; ks < 64; ++ks) {
        bf16x8 a = *(const bf16x8*)(hcat + (size_t)mrow*2048 + ks*32 + (lane>>4)*8);
        bf16x8 b = *(const bf16x8*)(wlds + (lane&15)*2056 + ks*32 + (lane>>4)*8);
        acc = MFMA16(a, b, acc);
    }
    const int c = n0 + (lane & 15);
    const float g = gamma[c], bt = beta[c], mn = mean[c], lb = lin_b[c];
    const float iv = rsqrtf(var[c] + 1e-5f);
    #pragma unroll
    for (int r = 0; r < 4; ++r) {
        int b_ = wave*16 + (lane>>4)*4 + r;
        float logit = acc[r] + lb;
        out[(size_t)b_*NC_ + c] = g*(logit - mn)*iv + bt;
    }
}

// ---------------- host ----------------
extern "C" void kernel_launch(void* const* d_in, const int* in_sizes, int n_in,
                              void* d_out, int out_size, void* d_ws, size_t ws_size,
                              hipStream_t stream) {
    const int*   wi      = (const int*)d_in[0];
    const int*   pi      = (const int*)d_in[1];
    const int*   ii      = (const int*)d_in[2];
    const int*   ti      = (const int*)d_in[3];
    const int*   mi      = (const int*)d_in[4];
    const int*   lengths = (const int*)d_in[5];
    const float* hidden  = (const float*)d_in[6];
    const float* we      = (const float*)d_in[7];
    const float* pe      = (const float*)d_in[8];
    const float* ie      = (const float*)d_in[9];
    const float* te      = (const float*)d_in[10];
    const float* me      = (const float*)d_in[11];
    const float* w_ih_f  = (const float*)d_in[12];
    const float* w_hh_f  = (const float*)d_in[13];
    const float* b_ih_f  = (const float*)d_in[14];
    const float* b_hh_f  = (const float*)d_in[15];
    const float* w_ih_b  = (const float*)d_in[16];
    const float* w_hh_b  = (const float*)d_in[17];
    const float* b_ih_b  = (const float*)d_in[18];
    const float* b_hh_b  = (const float*)d_in[19];
    const float* lin_w   = (const float*)d_in[20];
    const float* lin_b   = (const float*)d_in[21];
    const float* gamma   = (const float*)d_in[22];
    const float* beta    = (const float*)d_in[23];
    const float* mean    = (const float*)d_in[24];
    const float* var     = (const float*)d_in[25];
    float* out = (float*)d_out;

    if (ws_size < WS_NEED) return;

    char* ws = (char*)d_ws;
    __hip_bfloat16* FEAT = (__hip_bfloat16*)(ws + OFF_FEAT);
    __hip_bfloat16* WIHF = (__hip_bfloat16*)(ws + OFF_WIHF);
    __hip_bfloat16* WIHB = (__hip_bfloat16*)(ws + OFF_WIHB);
    __hip_bfloat16* WHH  = (__hip_bfloat16*)(ws + OFF_WHH);   // [2][3072][1024]
    __hip_bfloat16* LINW = (__hip_bfloat16*)(ws + OFF_LINW);
    float* BIHF = (float*)(ws + OFF_BIHF);
    float* BIHB = (float*)(ws + OFF_BIHB);
    float* BHH  = (float*)(ws + OFF_BHH);                      // [2][3072]
    __hip_bfloat16* XP   = (__hip_bfloat16*)(ws + OFF_XP);     // [2][32768][3072]
    __hip_bfloat16* HBF  = (__hip_bfloat16*)(ws + OFF_HBF);
    __hip_bfloat16* HCAT = (__hip_bfloat16*)(ws + OFF_HCAT);
    unsigned* BAR = (unsigned*)(ws + OFF_BAR);
    float* HIDO = out + (size_t)B_*NC_;

    // weight prep
    cvt_pad_3h<<<(G3*512 + 255)/256, 256, 0, stream>>>(w_ih_f, WIHF, FEAT_C, FEAT_P);
    cvt_pad_3h<<<(G3*512 + 255)/256, 256, 0, stream>>>(w_ih_b, WIHB, FEAT_C, FEAT_P);
    cvt_pad_3h<<<(G3*1024 + 255)/256, 256, 0, stream>>>(w_hh_f, WHH, H_, HP);
    cvt_pad_3h<<<(G3*1024 + 255)/256, 256, 0, stream>>>(w_hh_b, WHH + (size_t)G3*HP, H_, HP);
    cvt_pad<<<(NC_*2048 + 255)/256, 256, 0, stream>>>(lin_w, LINW, NC_, NC_, 2048);
    pad_b3h<<<(G3 + 255)/256, 256, 0, stream>>>(b_ih_f, BIHF);
    pad_b3h<<<(G3 + 255)/256, 256, 0, stream>>>(b_ih_b, BIHB);
    pad_b3h<<<(G3 + 255)/256, 256, 0, stream>>>(b_hh_f, BHH);
    pad_b3h<<<(G3 + 255)/256, 256, 0, stream>>>(b_hh_b, BHH + G3);

    // embeddings
    embed_k<<<NROWS, 256, 0, stream>>>(wi, pi, ii, ti, mi, we, pe, ie, te, me, FEAT);

    // input projections (both directions)
    dim3 gg(NROWS/128, G3/128);
    gemm_xp<<<gg, 256, 0, stream>>>(FEAT, WIHF, BIHF, lengths, XP, 0);
    gemm_xp<<<gg, 256, 0, stream>>>(FEAT, WIHB, BIHB, lengths, XP + (size_t)NROWS*G3, 1);

    // recurrence (single persistent cooperative kernel)
    init_h<<<(2*B_*HP + 255)/256, 256, 0, stream>>>(hidden, HBF);
    bar_init<<<8, 256, 0, stream>>>(BAR);
    {
        void* args[] = { (void*)&WHH, (void*)&BHH, (void*)&XP, (void*)&lengths,
                         (void*)&hidden, (void*)&HBF, (void*)&HCAT, (void*)&HIDO, (void*)&BAR };
        hipLaunchCooperativeKernel((const void*)gru_persist, dim3(256), dim3(512),
                                   args, 0, stream);
    }

    // head
    lin_bn_k<<<NC_/16, 256, 0, stream>>>(HCAT, LINW, lin_b, gamma, beta, mean, var, out);
}

// Round 13
// 2799.019 us; speedup vs baseline: 2.0322x; 1.0162x over previous
//
#include <hip/hip_runtime.h>
#include <hip/hip_bf16.h>

// ---------------- types ----------------
typedef __attribute__((ext_vector_type(8))) short bf16x8;   // 8 x bf16 (4 VGPRs)
typedef __attribute__((ext_vector_type(4))) float f32x4;

#define MFMA16(a,b,c) __builtin_amdgcn_mfma_f32_16x16x32_bf16((a),(b),(c),0,0,0)

__device__ __forceinline__ float sigmf(float x){ return 1.f/(1.f + __expf(-x)); }
__device__ __forceinline__ float tanh_fast(float x){
    float e = __expf(-2.f*fabsf(x));
    float t = (1.f-e)/(1.f+e);
    return x < 0.f ? -t : t;
}

#define AS1 __attribute__((address_space(1)))
#define AS3 __attribute__((address_space(3)))
__device__ __forceinline__ void gll16(const void* g, void* l) {
    __builtin_amdgcn_global_load_lds((const AS1 unsigned int*)g, (AS3 unsigned int*)l, 16, 0, 0);
}

// plain cached 16B load via asm (result can't be rematerialized -> stays on-chip)
__device__ __forceinline__ bf16x8 load16_asm(const __hip_bfloat16* p) {
    bf16x8 v;
    asm volatile("global_load_dwordx4 %0, %1, off" : "=v"(v) : "v"(p));
    return v;
}
// L3-coherent 16B load: bypass L1+L2 (sc0 sc1)
__device__ __forceinline__ bf16x8 load16_sc(const __hip_bfloat16* p) {
    bf16x8 v;
    asm volatile("global_load_dwordx4 %0, %1, off sc0 sc1" : "=v"(v) : "v"(p) : "memory");
    return v;
}
// L3-coherent 2B store (write-through past L1/L2)
__device__ __forceinline__ void store2_sc(__hip_bfloat16* p, float v) {
    __hip_bfloat16 b = __float2bfloat16(v);
    unsigned int u = *reinterpret_cast<unsigned short*>(&b);
    asm volatile("global_store_short %0, %1, off sc0 sc1" :: "v"(p), "v"(u) : "memory");
}
// L3-coherent 4B store
__device__ __forceinline__ void store4_sc(unsigned* p, unsigned v) {
    asm volatile("global_store_dword %0, %1, off sc0 sc1" :: "v"(p), "v"(v) : "memory");
}
// L3-coherent 4B poll load
__device__ __forceinline__ unsigned poll_sc(const unsigned* p) {
    unsigned v;
    asm volatile("global_load_dword %0, %1, off sc0 sc1\n\ts_waitcnt vmcnt(0)"
                 : "=v"(v) : "v"(p) : "memory");
    return v;
}
// cached 2B load (xp stream), asm so issue point is pinned
__device__ __forceinline__ unsigned ld2_g(const __hip_bfloat16* p) {
    unsigned v;
    asm volatile("global_load_ushort %0, %1, off" : "=v"(v) : "v"(p));
    return v;
}

// ---------------- problem constants ----------------
#define B_   64
#define T_   512
#define H_   1000
#define HP   1024        // padded H
#define G3   3072        // 3*HP
#define NC_  2000
#define FEAT_C 500
#define FEAT_P 512
#define NROWS 32768      // B_*T_

// ---------------- ws layout (bytes) ----------------
#define OFF_FEAT  ((size_t)0)                       // 32768*512*2      = 33,554,432
#define OFF_WIHF  (OFF_FEAT + 33554432ull)          // 3072*512*2
#define OFF_WIHB  (OFF_WIHF + 3145728ull)
#define OFF_WHH   (OFF_WIHB + 3145728ull)           // [2][3072][1024] bf16 = 12,582,912
#define OFF_LINW  (OFF_WHH + 12582912ull)           // 2000*2048*2 = 8,192,000
#define OFF_BIHF  (OFF_LINW + 8192000ull)           // 3072*4
#define OFF_BIHB  (OFF_BIHF + 12288ull)
#define OFF_BHH   (OFF_BIHB + 12288ull)             // [2][3072] f32 = 24,576
#define OFF_XP    (OFF_BHH + 24576ull)              // [2][32768][3072] bf16 = 402,653,184
#define OFF_HBF   (OFF_XP + 402653184ull)           // [2 parity][2*64][1024] bf16 = 524,288
#define OFF_HCAT  (OFF_HBF + 524288ull)             // [64][2048] bf16 = 262,144
#define OFF_BAR   (OFF_HCAT + 262144ull)            // 4 groups x 2048 B = 8192
#define WS_NEED   (OFF_BAR + 8192ull)

// ---------------- weight prep ----------------
__global__ void cvt_pad_3h(const float* __restrict__ src, __hip_bfloat16* __restrict__ dst,
                           int C, int Cp) {
    size_t i = (size_t)blockIdx.x*blockDim.x + threadIdx.x;
    size_t total = (size_t)G3 * Cp;
    if (i >= total) return;
    int r = (int)(i / Cp), c = (int)(i % Cp);
    int chunk = r >> 10, j = r & 1023;
    float v = (j < H_ && c < C) ? src[((size_t)chunk*H_ + j)*C + c] : 0.f;
    dst[i] = __float2bfloat16(v);
}

__global__ void cvt_pad(const float* __restrict__ src, __hip_bfloat16* __restrict__ dst,
                        int R, int C, int Cp) {
    size_t i = (size_t)blockIdx.x*blockDim.x + threadIdx.x;
    size_t total = (size_t)R * Cp;
    if (i >= total) return;
    int r = (int)(i / Cp), c = (int)(i % Cp);
    float v = (c < C) ? src[(size_t)r*C + c] : 0.f;
    dst[i] = __float2bfloat16(v);
}

__global__ void pad_b3h(const float* __restrict__ src, float* __restrict__ dst) {
    int i = blockIdx.x*blockDim.x + threadIdx.x;
    if (i >= G3) return;
    int chunk = i >> 10, j = i & 1023;
    dst[i] = (j < H_) ? src[chunk*H_ + j] : 0.f;
}

// ---------------- embedding gather ----------------
__global__ __launch_bounds__(256)
void embed_k(const int* __restrict__ wi, const int* __restrict__ pi, const int* __restrict__ ii,
             const int* __restrict__ ti, const int* __restrict__ mi,
             const float* __restrict__ we, const float* __restrict__ pe, const float* __restrict__ ie,
             const float* __restrict__ te, const float* __restrict__ me,
             __hip_bfloat16* __restrict__ feat) {
    int r = blockIdx.x;          // b*512 + t
    int iw = wi[r], ip = pi[r], ib = ii[r], it = ti[r], im = mi[r];
    #pragma unroll
    for (int q = 0; q < 2; ++q) {
        int c = threadIdx.x + q*256;
        float v;
        if      (c < 300) v = we[(size_t)iw*300 + c];
        else if (c < 350) v = pe[ip*50 + (c-300)];
        else if (c < 400) v = ie[ib*50 + (c-350)];
        else if (c < 450) v = te[it*50 + (c-400)];
        else if (c < 500) v = me[im*50 + (c-450)];
        else              v = 0.f;
        feat[(size_t)r*FEAT_P + c] = __float2bfloat16(v);
    }
}

// ---------------- input projection GEMM (bf16 MFMA, 128x128x64 tiles, global_load_lds) ----------------
// b-major M-tiling: tile bm -> batch row b = bm>>2, t-range tbase = (bm&3)*128.
// Whole tile skipped when tbase >= lengths[b] (xp rows t >= len[b] are never
// consumed by the recurrence -- gate output is discarded by the t<myLen select).
// A-loads: 128 CONTIGUOUS feat rows (same b, consecutive t) -> better L2 locality.
// Output row remap: r_out = (tbase+row)*64 + b (xp layout [t*64+b] unchanged).
__global__ __launch_bounds__(256)
void gemm_xp(const __hip_bfloat16* __restrict__ feat,  // [32768][512]
             const __hip_bfloat16* __restrict__ W,     // [3072][512]
             const float* __restrict__ bias,           // [3072]
             const int* __restrict__ lengths,
             __hip_bfloat16* __restrict__ xp,          // [32768][3072]
             int dir) {
    __shared__ char smem_raw[32768];
    __hip_bfloat16* As = (__hip_bfloat16*)smem_raw;            // [128][64]
    __hip_bfloat16* Bs = (__hip_bfloat16*)(smem_raw + 16384);  // [128][64]
    const int tid = threadIdx.x;
    const int wave = tid >> 6, lane = tid & 63;
    const int bm = blockIdx.x, bn = blockIdx.y;
    const int wm = wave >> 1, wn = wave & 1;

    const int b     = bm >> 2;
    const int tbase = (bm & 3) << 7;
    const int L     = lengths[b];
    if (tbase >= L) return;          // block-uniform early exit: rows unused downstream

    int arow_src[4];
    #pragma unroll
    for (int q = 0; q < 4; ++q) {
        int flat = q*256 + tid;
        int row = flat >> 3;
        int t = tbase + row;
        int src_t;
        if (dir == 0) src_t = t;
        else { src_t = L - 1 - t; src_t = src_t < 0 ? 0 : src_t; }
        arow_src[q] = b*T_ + src_t;
    }

    f32x4 acc[4][4];
    #pragma unroll
    for (int i = 0; i < 4; ++i)
        #pragma unroll
        for (int j = 0; j < 4; ++j) acc[i][j] = (f32x4){0.f,0.f,0.f,0.f};

    for (int kt = 0; kt < 8; ++kt) {
        int k0 = kt*64;
        #pragma unroll
        for (int q = 0; q < 4; ++q) {
            int flat = q*256 + tid;
            int row = flat >> 3, c8 = flat & 7;
            gll16(feat + (size_t)arow_src[q]*FEAT_P + k0 + c8*8,
                  As + (q*256 + wave*64)*8);
            gll16(W + (size_t)(bn*128 + row)*FEAT_P + k0 + c8*8,
                  Bs + (q*256 + wave*64)*8);
        }
        __syncthreads();
        #pragma unroll
        for (int ks = 0; ks < 2; ++ks) {
            bf16x8 af[4], bfr[4];
            #pragma unroll
            for (int i = 0; i < 4; ++i)
                af[i] = *(const bf16x8*)(As + (wm*64 + i*16 + (lane&15))*64 + ks*32 + (lane>>4)*8);
            #pragma unroll
            for (int j = 0; j < 4; ++j)
                bfr[j] = *(const bf16x8*)(Bs + (wn*64 + j*16 + (lane&15))*64 + ks*32 + (lane>>4)*8);
            #pragma unroll
            for (int i = 0; i < 4; ++i)
                #pragma unroll
                for (int j = 0; j < 4; ++j)
                    acc[i][j] = MFMA16(af[i], bfr[j], acc[i][j]);
        }
        __syncthreads();
    }

    __hip_bfloat16* Cs = (__hip_bfloat16*)smem_raw;  // [128][128]
    #pragma unroll
    for (int j = 0; j < 4; ++j) {
        int col_l = wn*64 + j*16 + (lane & 15);
        float bs = bias[bn*128 + col_l];
        #pragma unroll
        for (int i = 0; i < 4; ++i) {
            #pragma unroll
            for (int r = 0; r < 4; ++r) {
                int row_l = wm*64 + i*16 + (lane>>4)*4 + r;
                Cs[row_l*128 + col_l] = __float2bfloat16(acc[i][j][r] + bs);
            }
        }
    }
    __syncthreads();
    #pragma unroll
    for (int q = 0; q < 8; ++q) {
        int flat = q*256 + tid;       // 16B units, 2048 total
        int row = flat >> 4, c8 = flat & 15;
        bf16x8 v = *(const bf16x8*)(Cs + row*128 + c8*8);
        size_t r_out = (size_t)(tbase + row)*B_ + b;
        *(bf16x8*)(xp + r_out*G3 + bn*128 + c8*8) = v;
    }
}

// ---------------- h bf16 ping-pong init ----------------
__global__ void init_h(const float* __restrict__ hidden, __hip_bfloat16* __restrict__ hbf) {
    int i = blockIdx.x*blockDim.x + threadIdx.x;   // over 2*64*1024
    if (i >= 2*B_*HP) return;
    int row = i >> 10, j = i & 1023;               // row = dir*64+b
    int dir = row >> 6, b = row & 63;
    float v = (j < H_) ? hidden[((size_t)dir*B_ + b)*H_ + j] : 0.f;
    __hip_bfloat16 bv = __float2bfloat16(v);
    hbf[i] = bv;                 // parity 0
    hbf[2*B_*HP + i] = bv;       // parity 1
}

__global__ void bar_init(unsigned* bar) {
    int i = blockIdx.x*blockDim.x + threadIdx.x;   // 8 x 256 = 2048 u32 = 8 KB
    if (i < 2048) bar[i] = 0u;
}

// ---------------- persistent bidirectional GRU recurrence (cooperative) ----------------
// 256 blocks x 512 thr (8 waves). Barrier groups of 64 blocks: g=(dir,bh).
// Weights pinned in regs/AGPRs via asm loads. h exchange via L3 (sc0 sc1).
// Barrier (two-level tree, BEST MEASURED 4.72us/step): arrive = 64 atomicAdds
// spread over 8 lines; aggregator block (ug==0) polls the 8 lines with one
// 64-lane load + __all, then single-writer-stores the release flag; remaining
// blocks tight-poll the read-only flag line. Monotone counters, no resets.
// xp(t+1) scalars prefetched into regs across the barrier.
__global__ __launch_bounds__(512, 2)
void gru_persist(const __hip_bfloat16* __restrict__ whh,   // [2][3072][1024]
                 const float* __restrict__ bhh,            // [2][3072]
                 const __hip_bfloat16* __restrict__ xp,    // [2][32768][3072]
                 const int* __restrict__ lengths,
                 const float* __restrict__ hidden,         // [2][64][1000]
                 __hip_bfloat16* __restrict__ hbf,         // [2][128][1024]
                 __hip_bfloat16* __restrict__ hcat,        // [64][2048]
                 float* __restrict__ hid_o,                // d_out + 64*2000
                 unsigned* __restrict__ bar) {
    __shared__ float part[2][4][3][256];   // [bg][kh][gate][lane*4 + r]
    const int blk = blockIdx.x;
    const int r8  = blk & 7, q8 = blk >> 3;
    const int g   = r8 >> 1;                 // barrier group 0..3
    const int dir = g >> 1, bh = g & 1;
    const int ug  = q8*2 + (r8 & 1);         // unit group 0..63
    const int w    = threadIdx.x >> 6;
    const int lane = threadIdx.x & 63;
    const int bg  = w >> 2;     // 0..1
    const int kh  = w & 3;      // 0..3 (K-quarter)
    const int u   = lane & 15;
    const int rg  = lane >> 4;  // 0..3

    const int j   = ug*16 + u;                      // hidden unit (0..1023)
    const int bA  = bh*32 + bg*16 + u;              // A-fragment batch row
    const int bF  = bh*32 + bg*16 + rg*4 + kh;      // finalize batch row
    const int myLen  = lengths[bF];
    const int lenBlk = lengths[bh*32];              // group-uniform (sorted desc)

    unsigned* cntg  = bar + g*512;                  // 8 arrive lines, 128B stride
    unsigned* flagp = bar + g*512 + 256;            // release flag line

    const float bhr = bhh[dir*G3 + j];
    const float bhz = bhh[dir*G3 + HP + j];
    const float bhn = bhh[dir*G3 + 2*HP + j];
    float hreg = (j < H_) ? hidden[((size_t)dir*B_ + bF)*H_ + j] : 0.f;

    // weights -> registers (3 gates x 8 K-slices of this wave's K-quarter), pinned via asm
    bf16x8 wf0[8], wf1[8], wf2[8];
    {
        const __hip_bfloat16* wb = whh + (size_t)dir*G3*HP + (size_t)j*HP + kh*256 + rg*8;
        #pragma unroll
        for (int ks = 0; ks < 8; ++ks) {
            wf0[ks] = load16_asm(wb + ks*32);
            wf1[ks] = load16_asm(wb + (size_t)HP*HP + ks*32);
            wf2[ks] = load16_asm(wb + (size_t)2*HP*HP + ks*32);
        }
        asm volatile("s_waitcnt vmcnt(0)" ::: "memory");
        __builtin_amdgcn_sched_barrier(0);
    }

    const size_t hrowA = (size_t)(dir*B_ + bA)*HP + kh*256 + rg*8;
    const size_t hidxF = (size_t)(dir*B_ + bF)*HP + j;
    const size_t xbase = (size_t)dir*NROWS*G3 + (size_t)bF*G3 + j;

    // prefetch xp(t=0) scalars (drained by the first S1 vmcnt(0))
    unsigned pxr, pxz, pxn;
    {
        const __hip_bfloat16* x0 = xp + xbase;
        pxr = ld2_g(x0); pxz = ld2_g(x0 + HP); pxn = ld2_g(x0 + 2*HP);
    }

    for (int t = 0; t < lenBlk; ++t) {
        const int cur = t & 1, prev = cur ^ 1;
        // h A-fragments from L3 (written cross-XCD last step)
        const __hip_bfloat16* ha = hbf + (size_t)prev*2*B_*HP + hrowA;
        bf16x8 af[8];
        #pragma unroll
        for (int ks = 0; ks < 8; ++ks) af[ks] = load16_sc(ha + ks*32);
        asm volatile("s_waitcnt vmcnt(0)" ::: "memory");
        __builtin_amdgcn_sched_barrier(0);

        f32x4 a0 = {0.f,0.f,0.f,0.f}, a1 = {0.f,0.f,0.f,0.f}, a2 = {0.f,0.f,0.f,0.f};
        #pragma unroll
        for (int ks = 0; ks < 8; ++ks) {
            a0 = MFMA16(af[ks], wf0[ks], a0);
            a1 = MFMA16(af[ks], wf1[ks], a1);
            a2 = MFMA16(af[ks], wf2[ks], a2);
        }

        // consume prefetched xp(t)
        float xr = __uint_as_float(pxr << 16);
        float xz = __uint_as_float(pxz << 16);
        float xn = __uint_as_float(pxn << 16);

        *(f32x4*)&part[bg][kh][0][lane*4] = a0;
        *(f32x4*)&part[bg][kh][1][lane*4] = a1;
        *(f32x4*)&part[bg][kh][2][lane*4] = a2;
        __syncthreads();
        float sr = 0.f, sz = 0.f, sn = 0.f;
        #pragma unroll
        for (int q = 0; q < 4; ++q) {
            sr += part[bg][q][0][lane*4 + kh];
            sz += part[bg][q][1][lane*4 + kh];
            sn += part[bg][q][2][lane*4 + kh];
        }
        float rr = sigmf(xr + sr + bhr);
        float zz = sigmf(xz + sz + bhz);
        float nn = tanh_fast(xn + rr*(sn + bhn));
        float hnew = (t < myLen) ? ((1.f - zz)*nn + zz*hreg) : hreg;
        hreg = hnew;
        store2_sc(hbf + (size_t)cur*2*B_*HP + hidxF, hnew);   // through to L3
        asm volatile("s_waitcnt vmcnt(0)" ::: "memory");      // per-wave drain
        __syncthreads();                                      // all waves drained

        if (t + 1 < lenBlk) {                                 // group-uniform predicate
            // prefetch xp(t+1); stays in flight across the barrier
            {
                const __hip_bfloat16* xnp = xp + xbase + (size_t)(t+1)*B_*G3;
                pxr = ld2_g(xnp); pxz = ld2_g(xnp + HP); pxn = ld2_g(xnp + 2*HP);
            }
            if (w == 0) {
                const unsigned tgt = (unsigned)(t + 1);
                if (lane == 0) atomicAdd(cntg + (ug >> 3)*32, 1u);   // parallel arrive
                if (ug == 0) {
                    // aggregator: one 64-lane load covers the 8 arrive lines
                    for (;;) {
                        unsigned v = poll_sc(cntg + (lane & 7)*32);
                        if (__all((int)(v >= 8u*tgt))) break;
                    }
                    if (lane == 0) store4_sc(flagp, tgt);            // single-writer release
                } else {
                    if (lane == 0) { while (poll_sc(flagp) < tgt) { } }
                }
            }
            __syncthreads();
        }
    }

    // outputs straight from registers (+ zero hcat tail cols 2000..2047)
    if (j < H_) {
        hid_o[((size_t)dir*B_ + bF)*H_ + j] = hreg;
        hcat[(size_t)bF*2048 + dir*H_ + j] = __float2bfloat16(hreg);
    } else {
        hcat[(size_t)bF*2048 + 2000 + dir*24 + (j - H_)] = __float2bfloat16(0.f);
    }
}

// ---------------- final linear + BN ----------------
__global__ __launch_bounds__(256)
void lin_bn_k(const __hip_bfloat16* __restrict__ hcat,  // [64][2048]
              const __hip_bfloat16* __restrict__ linw,  // [2000][2048]
              const float* __restrict__ lin_b, const float* __restrict__ gamma,
              const float* __restrict__ beta, const float* __restrict__ mean,
              const float* __restrict__ var,
              float* __restrict__ out) {                // [64][2000]
    __shared__ __hip_bfloat16 wlds[16*2056];
    const int n0 = blockIdx.x*16;
    const int tid = threadIdx.x;
    #pragma unroll
    for (int q = 0; q < 16; ++q) {
        int flat8 = q*256 + tid;
        int row = flat8 >> 8, c8 = flat8 & 255;
        bf16x8 v = *(const bf16x8*)(linw + (size_t)(n0+row)*2048 + c8*8);
        *(bf16x8*)(wlds + row*2056 + c8*8) = v;
    }
    __syncthreads();
    const int wave = tid >> 6, lane = tid & 63;
    const int mrow = wave*16 + (lane & 15);
    f32x4 acc = {0.f,0.f,0.f,0.f};
    for (int ks = 0; ks < 64; ++ks) {
        bf16x8 a = *(const bf16x8*)(hcat + (size_t)mrow*2048 + ks*32 + (lane>>4)*8);
        bf16x8 b = *(const bf16x8*)(wlds + (lane&15)*2056 + ks*32 + (lane>>4)*8);
        acc = MFMA16(a, b, acc);
    }
    const int c = n0 + (lane & 15);
    const float g = gamma[c], bt = beta[c], mn = mean[c], lb = lin_b[c];
    const float iv = rsqrtf(var[c] + 1e-5f);
    #pragma unroll
    for (int r = 0; r < 4; ++r) {
        int b_ = wave*16 + (lane>>4)*4 + r;
        float logit = acc[r] + lb;
        out[(size_t)b_*NC_ + c] = g*(logit - mn)*iv + bt;
    }
}

// ---------------- host ----------------
extern "C" void kernel_launch(void* const* d_in, const int* in_sizes, int n_in,
                              void* d_out, int out_size, void* d_ws, size_t ws_size,
                              hipStream_t stream) {
    const int*   wi      = (const int*)d_in[0];
    const int*   pi      = (const int*)d_in[1];
    const int*   ii      = (const int*)d_in[2];
    const int*   ti      = (const int*)d_in[3];
    const int*   mi      = (const int*)d_in[4];
    const int*   lengths = (const int*)d_in[5];
    const float* hidden  = (const float*)d_in[6];
    const float* we      = (const float*)d_in[7];
    const float* pe      = (const float*)d_in[8];
    const float* ie      = (const float*)d_in[9];
    const float* te      = (const float*)d_in[10];
    const float* me      = (const float*)d_in[11];
    const float* w_ih_f  = (const float*)d_in[12];
    const float* w_hh_f  = (const float*)d_in[13];
    const float* b_ih_f  = (const float*)d_in[14];
    const float* b_hh_f  = (const float*)d_in[15];
    const float* w_ih_b  = (const float*)d_in[16];
    const float* w_hh_b  = (const float*)d_in[17];
    const float* b_ih_b  = (const float*)d_in[18];
    const float* b_hh_b  = (const float*)d_in[19];
    const float* lin_w   = (const float*)d_in[20];
    const float* lin_b   = (const float*)d_in[21];
    const float* gamma   = (const float*)d_in[22];
    const float* beta    = (const float*)d_in[23];
    const float* mean    = (const float*)d_in[24];
    const float* var     = (const float*)d_in[25];
    float* out = (float*)d_out;

    if (ws_size < WS_NEED) return;

    char* ws = (char*)d_ws;
    __hip_bfloat16* FEAT = (__hip_bfloat16*)(ws + OFF_FEAT);
    __hip_bfloat16* WIHF = (__hip_bfloat16*)(ws + OFF_WIHF);
    __hip_bfloat16* WIHB = (__hip_bfloat16*)(ws + OFF_WIHB);
    __hip_bfloat16* WHH  = (__hip_bfloat16*)(ws + OFF_WHH);   // [2][3072][1024]
    __hip_bfloat16* LINW = (__hip_bfloat16*)(ws + OFF_LINW);
    float* BIHF = (float*)(ws + OFF_BIHF);
    float* BIHB = (float*)(ws + OFF_BIHB);
    float* BHH  = (float*)(ws + OFF_BHH);                      // [2][3072]
    __hip_bfloat16* XP   = (__hip_bfloat16*)(ws + OFF_XP);     // [2][32768][3072]
    __hip_bfloat16* HBF  = (__hip_bfloat16*)(ws + OFF_HBF);
    __hip_bfloat16* HCAT = (__hip_bfloat16*)(ws + OFF_HCAT);
    unsigned* BAR = (unsigned*)(ws + OFF_BAR);
    float* HIDO = out + (size_t)B_*NC_;

    // weight prep
    cvt_pad_3h<<<(G3*512 + 255)/256, 256, 0, stream>>>(w_ih_f, WIHF, FEAT_C, FEAT_P);
    cvt_pad_3h<<<(G3*512 + 255)/256, 256, 0, stream>>>(w_ih_b, WIHB, FEAT_C, FEAT_P);
    cvt_pad_3h<<<(G3*1024 + 255)/256, 256, 0, stream>>>(w_hh_f, WHH, H_, HP);
    cvt_pad_3h<<<(G3*1024 + 255)/256, 256, 0, stream>>>(w_hh_b, WHH + (size_t)G3*HP, H_, HP);
    cvt_pad<<<(NC_*2048 + 255)/256, 256, 0, stream>>>(lin_w, LINW, NC_, NC_, 2048);
    pad_b3h<<<(G3 + 255)/256, 256, 0, stream>>>(b_ih_f, BIHF);
    pad_b3h<<<(G3 + 255)/256, 256, 0, stream>>>(b_ih_b, BIHB);
    pad_b3h<<<(G3 + 255)/256, 256, 0, stream>>>(b_hh_f, BHH);
    pad_b3h<<<(G3 + 255)/256, 256, 0, stream>>>(b_hh_b, BHH + G3);

    // embeddings
    embed_k<<<NROWS, 256, 0, stream>>>(wi, pi, ii, ti, mi, we, pe, ie, te, me, FEAT);

    // input projections (both directions), length-aware b-major tiling
    dim3 gg(NROWS/128, G3/128);
    gemm_xp<<<gg, 256, 0, stream>>>(FEAT, WIHF, BIHF, lengths, XP, 0);
    gemm_xp<<<gg, 256, 0, stream>>>(FEAT, WIHB, BIHB, lengths, XP + (size_t)NROWS*G3, 1);

    // recurrence (single persistent cooperative kernel)
    init_h<<<(2*B_*HP + 255)/256, 256, 0, stream>>>(hidden, HBF);
    bar_init<<<8, 256, 0, stream>>>(BAR);
    {
        void* args[] = { (void*)&WHH, (void*)&BHH, (void*)&XP, (void*)&lengths,
                         (void*)&hidden, (void*)&HBF, (void*)&HCAT, (void*)&HIDO, (void*)&BAR };
        hipLaunchCooperativeKernel((const void*)gru_persist, dim3(256), dim3(512),
                                   args, 0, stream);
    }

    // head
    lin_bn_k<<<NC_/16, 256, 0, stream>>>(HCAT, LINW, lin_b, gamma, beta, mean, var, out);
}